// Round 9
// baseline (350.595 us; speedup 1.0000x reference)
//
#include <hip/hip_runtime.h>
#include <hip/hip_bf16.h>

// Problem constants
#define BGR   256                 // graphs
#define NPG1  512                 // nodes per graph (input)
#define DEG   16
#define EPG   (NPG1 * DEG)        // 8192 edges per graph
#define LB    5                   // lookback features
#define DIM   64
#define OUTF  6
#define NN    (BGR * NPG1)        // 131,072
#define EDG   (BGR * EPG)         // 2,097,152
#define K1    410                 // ceil(0.8*512)
#define K2    328                 // ceil(0.8*410)
#define N1    (BGR * K1)          // 104,960
#define CSRW  48                  // CSR slots per node (max pooled in-deg ~35)
#define SPLIT 4                   // s1 aggregation sub-blocks per graph
#define EPS   (EPG / SPLIT)       // 2048 edges per sub-block
#define GRIDW (N1 / 64)           // 1640 gemm blocks (64 rows each)
#define GRIDA (N1 / 16)           // 6560 gather2 blocks

// ---------------------------------------------------------------------------
// s1_agg: per (graph, quarter) block aggregates 2048 edges into LDS, writes
// PARTIAL sums + degrees to global (no global atomics).
__global__ __launch_bounds__(512)
void s1_agg_kernel(const float* __restrict__ x,
                   const int* __restrict__ eidx,
                   float* __restrict__ part_s,
                   int* __restrict__ part_d) {
    __shared__ __align__(16) float xl[NPG1 * LB];
    __shared__ __align__(16) float sums[NPG1 * LB];
    __shared__ int degi[NPG1];

    const int bid = blockIdx.x;               // g*SPLIT + p
    const int g = bid >> 2;
    const int p = bid & 3;
    const int t = threadIdx.x;
    const int* __restrict__ src = eidx;
    const int* __restrict__ dst = eidx + EDG;

    {
        const float4* x4 = (const float4*)(x + (size_t)g * (NPG1 * LB));
        float4* xl4 = (float4*)xl;
        float4* sm4 = (float4*)sums;
        const float4 z4 = make_float4(0.f, 0.f, 0.f, 0.f);
        #pragma unroll
        for (int k = 0; k < 2; ++k) {
            int i = k * 512 + t;
            if (i < NPG1 * LB / 4) { xl4[i] = x4[i]; sm4[i] = z4; }
        }
        degi[t] = 0;
    }
    __syncthreads();

    const int ebase = g * EPG + p * EPS;
    #pragma unroll
    for (int k = 0; k < EPS / 512; ++k) {     // 4 edges per thread
        int e = ebase + k * 512 + t;
        int s = src[e] & (NPG1 - 1);
        int d = dst[e] & (NPG1 - 1);
        #pragma unroll
        for (int j = 0; j < LB; ++j)
            unsafeAtomicAdd(&sums[d * LB + j], xl[s * LB + j]);
        atomicAdd(&degi[d], 1);
    }
    __syncthreads();

    {
        float4* ps4 = (float4*)(part_s + (size_t)bid * (NPG1 * LB));
        const float4* ls4 = (const float4*)sums;
        #pragma unroll
        for (int k = 0; k < 2; ++k) {
            int i = k * 512 + t;
            if (i < NPG1 * LB / 4) ps4[i] = ls4[i];
        }
        part_d[bid * NPG1 + t] = degi[t];
    }
}

// ---------------------------------------------------------------------------
// s1_score: node-parallel, full occupancy.
__global__ __launch_bounds__(256)
void s1_score_kernel(const float* __restrict__ x,
                     const float* __restrict__ part_s,
                     const int* __restrict__ part_d,
                     const float* __restrict__ Wl,
                     const float* __restrict__ bl,
                     const float* __restrict__ Wr,
                     const float* __restrict__ pw,
                     float* __restrict__ meanv,
                     float* __restrict__ sc1g) {
    const int n = blockIdx.x * 256 + threadIdx.x;    // grid = NN/256 exact
    const int g = n >> 9, lo = n & (NPG1 - 1);

    float s0 = 0.f, s1 = 0.f, s2 = 0.f, s3 = 0.f, s4 = 0.f;
    int dg = 0;
    #pragma unroll
    for (int p = 0; p < SPLIT; ++p) {
        const float* ps = part_s + (size_t)(g * SPLIT + p) * (NPG1 * LB) + lo * LB;
        s0 += ps[0]; s1 += ps[1]; s2 += ps[2]; s3 += ps[3]; s4 += ps[4];
        dg += part_d[(g * SPLIT + p) * NPG1 + lo];
    }
    const float invd = 1.f / fmaxf((float)dg, 1.f);
    float m[LB]  = { s0 * invd, s1 * invd, s2 * invd, s3 * invd, s4 * invd };
    float xv[LB];
    const float* xr = x + (size_t)n * LB;
    #pragma unroll
    for (int j = 0; j < LB; ++j) { xv[j] = xr[j]; meanv[(size_t)n * LB + j] = m[j]; }

    const float4* Wl4 = (const float4*)Wl;
    const float4* Wr4 = (const float4*)Wr;
    const float4* bl4 = (const float4*)bl;
    const float4* pw4 = (const float4*)pw;
    float p = 0.f, q = 0.f;
    #pragma unroll 4
    for (int d4 = 0; d4 < DIM / 4; ++d4) {
        float4 bb = bl4[d4];
        float4 ww = pw4[d4];
        float4 h = bb;
        #pragma unroll
        for (int j = 0; j < LB; ++j) {
            float4 a = Wl4[j * (DIM / 4) + d4];
            float4 b = Wr4[j * (DIM / 4) + d4];
            h.x += m[j] * a.x + xv[j] * b.x;
            h.y += m[j] * a.y + xv[j] * b.y;
            h.z += m[j] * a.z + xv[j] * b.z;
            h.w += m[j] * a.w + xv[j] * b.w;
        }
        h.x = fmaxf(h.x, 0.f); h.y = fmaxf(h.y, 0.f);
        h.z = fmaxf(h.z, 0.f); h.w = fmaxf(h.w, 0.f);
        p += h.x * ww.x + h.y * ww.y + h.z * ww.z + h.w * ww.w;
        q += ww.x * ww.x + ww.y * ww.y + ww.z * ww.z + ww.w * ww.w;
    }
    sc1g[n] = tanhf(p / sqrtf(q));
}

// ---------------------------------------------------------------------------
// s1_rankpool: per-graph rank + kept-row recompute + h1p + readout x1.
__global__ __launch_bounds__(512)
void s1_rankpool_kernel(const float* __restrict__ x,
                        const float* __restrict__ meanv,
                        const float* __restrict__ sc1g,
                        const float* __restrict__ Wl,
                        const float* __restrict__ bl,
                        const float* __restrict__ Wr,
                        float* __restrict__ h1p,
                        int* __restrict__ invr,
                        float* __restrict__ x1buf) {
    __shared__ __align__(16) float sc[NPG1];
    __shared__ int   rnk[NPG1];
    __shared__ float redmx[8 * DIM];
    __shared__ float redsm[8 * DIM];

    const int g = blockIdx.x, t = threadIdx.x;
    const int wid = t >> 6, lane = t & 63;

    sc[t] = sc1g[g * NPG1 + t];
    __syncthreads();

    {
        float my = sc[t];
        int r = 0;
        const float4* sc4 = (const float4*)sc;
        #pragma unroll 4
        for (int j4 = 0; j4 < NPG1 / 4; ++j4) {
            float4 v = sc4[j4];
            int j = 4 * j4;
            r += (v.x > my) | ((v.x == my) & (j     < t));
            r += (v.y > my) | ((v.y == my) & (j + 1 < t));
            r += (v.z > my) | ((v.z == my) & (j + 2 < t));
            r += (v.w > my) | ((v.w == my) & (j + 3 < t));
        }
        rnk[t] = r;
        invr[g * NPG1 + t] = (r < K1) ? r : -1;
    }
    __syncthreads();

    float wlv[LB], wrv[LB];
    #pragma unroll
    for (int j = 0; j < LB; ++j) { wlv[j] = Wl[j * DIM + lane]; wrv[j] = Wr[j * DIM + lane]; }
    const float blv = bl[lane];

    float mx = -INFINITY, sm = 0.f;
    for (int n = wid; n < NPG1; n += 8) {
        int r = rnk[n];
        if (r >= K1) continue;
        const float* mp = meanv + (size_t)(g * NPG1 + n) * LB;
        const float* xp = x + (size_t)(g * NPG1 + n) * LB;
        float al = 0.f, ar = 0.f;
        #pragma unroll
        for (int j = 0; j < LB; ++j) {
            al += mp[j] * wlv[j];
            ar += xp[j] * wrv[j];
        }
        float acc = fmaxf(blv + al + ar, 0.f);
        float v = acc * sc[n];
        h1p[((size_t)g * K1 + r) * DIM + lane] = v;
        mx = fmaxf(mx, v);
        sm += v;
    }
    redmx[wid * DIM + lane] = mx;
    redsm[wid * DIM + lane] = sm;
    __syncthreads();
    if (wid == 0) {
        float m2 = redmx[lane], s2 = redsm[lane];
        #pragma unroll
        for (int w = 1; w < 8; ++w) {
            m2 = fmaxf(m2, redmx[w * DIM + lane]);
            s2 += redsm[w * DIM + lane];
        }
        x1buf[g * 2 * DIM + lane]       = m2;
        x1buf[g * 2 * DIM + DIM + lane] = s2 * (1.0f / (float)K1);
    }
}

// ---------------------------------------------------------------------------
// csr_fill: edge-parallel. (csr tail slots stay garbage; gather2 predicates.)
__global__ __launch_bounds__(256)
void csr_fill_kernel(const int* __restrict__ eidx,
                     const int* __restrict__ invr,
                     int* __restrict__ csr,
                     int* __restrict__ indeg) {
    int e = blockIdx.x * 256 + threadIdx.x;       // grid = EDG/256 exact
    int s = eidx[e];
    int d = eidx[EDG + e];
    int rs = invr[s];
    int rd = invr[d];
    if ((rs | rd) < 0) return;
    int g = s >> 9;
    int gn = g * K1 + rd;
    int slot = atomicAdd(&indeg[gn], 1);
    csr[gn * CSRW + slot] = g * K1 + rs;
}

// ---------------------------------------------------------------------------
// gemmW: out[n,:] = in[n,:]@W (+bias). 256 thr = 4 waves x 16 rows; 16 KB LDS.
// Safe in-place when out==in: each block reads only its own 64 rows, and all
// reads complete before the stores.
template<bool BIAS>
__global__ __launch_bounds__(256)
void gemmW_kernel(const float* __restrict__ in,
                  float* __restrict__ outp,
                  const float* __restrict__ W,
                  const float* __restrict__ bias) {
    __shared__ __align__(16) float ws[DIM * DIM];      // 16 KB
    const int t = threadIdx.x, wid = t >> 6, lane = t & 63;
    {
        const float4* W4 = (const float4*)W;
        float4* ws4 = (float4*)ws;
        #pragma unroll
        for (int k = 0; k < 4; ++k) ws4[k * 256 + t] = W4[k * 256 + t];
    }
    __syncthreads();

    const int nb = blockIdx.x * 64 + wid * 16;         // grid = N1/64 exact
    float acc[16];
    #pragma unroll
    for (int i = 0; i < 16; ++i) acc[i] = 0.f;

    #pragma unroll 2
    for (int j4 = 0; j4 < DIM / 4; ++j4) {
        const int jb = 4 * j4 * DIM + lane;
        float w0 = ws[jb],           w1 = ws[jb + DIM];
        float w2 = ws[jb + 2 * DIM], w3 = ws[jb + 3 * DIM];
        #pragma unroll
        for (int i = 0; i < 16; ++i) {
            float4 a = *(const float4*)&in[(size_t)(nb + i) * DIM + 4 * j4];
            acc[i] += a.x * w0 + a.y * w1 + a.z * w2 + a.w * w3;
        }
    }
    const float bv = BIAS ? bias[lane] : 0.f;
    #pragma unroll
    for (int i = 0; i < 16; ++i)
        outp[(size_t)(nb + i) * DIM + lane] = acc[i] + bv;
}

// ---------------------------------------------------------------------------
// gather2: h2 = relu(invd * sum(Y_l[nbr]) + Y_r) in-place over Yr, + score2.
// Predicated gather (no CSR padding needed).
__global__ __launch_bounds__(256)
void gather2_kernel(const float* __restrict__ Yl,
                    float* __restrict__ Yh,      // Y_r in, h2 out (in-place)
                    const int* __restrict__ csr,
                    const int* __restrict__ indeg,
                    const float* __restrict__ pw,
                    float* __restrict__ sc2g) {
    const int t = threadIdx.x, wid = t >> 6, lane = t & 63;
    const int cid = ((int)blockIdx.x & 7) * (GRIDA / 8) + ((int)blockIdx.x >> 3);
    const int n0 = cid * 16 + wid * 4;

    const float pwv = pw[lane];
    float q = pwv * pwv;
    #pragma unroll
    for (int o = 32; o; o >>= 1) q += __shfl_xor(q, o);
    const float inv_nrm = 1.f / sqrtf(q);

    #pragma unroll
    for (int i = 0; i < 4; ++i) {
        const int n = n0 + i;
        const int dg = indeg[n];
        const int4* cr = (const int4*)&csr[n * CSRW];
        float acc = 0.f;
        #pragma unroll 2
        for (int kc = 0; 4 * kc < dg; ++kc) {
            int4 id = cr[kc];
            int k0 = 4 * kc;
            #define GACC(idv, kk)                                          \
            {   int   _id = ((kk) < dg) ? (idv) : 0;                       \
                float _v  = Yl[(size_t)_id * DIM + lane];                  \
                acc += ((kk) < dg) ? _v : 0.f; }
            GACC(id.x, k0) GACC(id.y, k0 + 1) GACC(id.z, k0 + 2) GACC(id.w, k0 + 3)
            #undef GACC
        }
        const float invd = 1.f / fmaxf((float)dg, 1.f);
        const float h = fmaxf(acc * invd + Yh[(size_t)n * DIM + lane], 0.f);
        Yh[(size_t)n * DIM + lane] = h;
        float p = h * pwv;
        #pragma unroll
        for (int o = 32; o; o >>= 1) p += __shfl_xor(p, o);
        if (lane == 0) sc2g[n] = tanhf(p * inv_nrm);
    }
}

// ---------------------------------------------------------------------------
// Pool2 + readout2 + final MLP (one block per graph).
__global__ __launch_bounds__(512)
void pool2_mlp_kernel(const float* __restrict__ sc2g,
                      const float* __restrict__ h2,
                      const float* __restrict__ x1buf,
                      const float* __restrict__ W1,
                      const float* __restrict__ b1,
                      const float* __restrict__ W2,
                      const float* __restrict__ b2,
                      float* __restrict__ out) {
    __shared__ __align__(16) float sc2[412];
    __shared__ int   rnk2[K1];
    __shared__ float redmx[8 * DIM];
    __shared__ float redsm[8 * DIM];
    __shared__ float zy[2 * DIM + DIM];

    const int g = blockIdx.x, t = threadIdx.x;
    const int wid = t >> 6, lane = t & 63;

    if (t < K1) sc2[t] = sc2g[g * K1 + t];
    if (t >= K1 && t < 412) sc2[t] = -INFINITY;
    __syncthreads();

    if (t < K1) {
        float my = sc2[t];
        int r = 0;
        const float4* sc4 = (const float4*)sc2;
        #pragma unroll 4
        for (int j4 = 0; j4 < 103; ++j4) {
            float4 v = sc4[j4];
            int j = 4 * j4;
            r += (v.x > my) | ((v.x == my) & (j     < t));
            r += (v.y > my) | ((v.y == my) & (j + 1 < t));
            r += (v.z > my) | ((v.z == my) & (j + 2 < t));
            r += (v.w > my) | ((v.w == my) & (j + 3 < t));
        }
        rnk2[t] = r;
    }
    __syncthreads();

    float mx = -INFINITY, sm = 0.f;
    for (int n = wid; n < K1; n += 8) {
        if (rnk2[n] < K2) {
            float v = h2[((size_t)g * K1 + n) * DIM + lane] * sc2[n];
            mx = fmaxf(mx, v);
            sm += v;
        }
    }
    redmx[wid * DIM + lane] = mx;
    redsm[wid * DIM + lane] = sm;
    __syncthreads();
    if (wid == 0) {
        float m2 = redmx[lane], s2 = redsm[lane];
        #pragma unroll
        for (int w = 1; w < 8; ++w) {
            m2 = fmaxf(m2, redmx[w * DIM + lane]);
            s2 += redsm[w * DIM + lane];
        }
        zy[lane]       = x1buf[g * 2 * DIM + lane]       + m2;
        zy[DIM + lane] = x1buf[g * 2 * DIM + DIM + lane] + s2 * (1.0f / (float)K2);
    }
    __syncthreads();

    if (t < DIM) {
        float a = b1[t];
        #pragma unroll 8
        for (int j = 0; j < 2 * DIM; ++j) a += zy[j] * W1[j * DIM + t];
        zy[2 * DIM + t] = fmaxf(a, 0.f);
    }
    __syncthreads();
    if (t < OUTF) {
        float a = b2[t];
        #pragma unroll
        for (int j = 0; j < DIM; ++j) a += zy[2 * DIM + j] * W2[j * OUTF + t];
        out[g * OUTF + t] = a;
    }
}

// ---------------------------------------------------------------------------
extern "C" void kernel_launch(void* const* d_in, const int* in_sizes, int n_in,
                              void* d_out, int out_size, void* d_ws, size_t ws_size,
                              hipStream_t stream) {
    (void)in_sizes; (void)n_in; (void)out_size; (void)ws_size;
    const float* x       = (const float*)d_in[0];
    const int*   eidx    = (const int*)d_in[1];
    const float* c1_Wl   = (const float*)d_in[2];
    const float* c1_bl   = (const float*)d_in[3];
    const float* c1_Wr   = (const float*)d_in[4];
    const float* pool1_w = (const float*)d_in[5];
    const float* c2_Wl   = (const float*)d_in[6];
    const float* c2_bl   = (const float*)d_in[7];
    const float* c2_Wr   = (const float*)d_in[8];
    const float* pool2_w = (const float*)d_in[9];
    const float* lin1_W  = (const float*)d_in[10];
    const float* lin1_b  = (const float*)d_in[11];
    const float* lin2_W  = (const float*)d_in[12];
    const float* lin2_b  = (const float*)d_in[13];
    float* out = (float*)d_out;

    // Workspace layout (256-aligned), ~76 MB with overlays
    char* w = (char*)d_ws;
    size_t off = 0;
    auto alloc = [&](size_t bytes) {
        void* p = w + off;
        off = (off + bytes + 255) & ~(size_t)255;
        return p;
    };
    float* h1p   = (float*)alloc((size_t)N1 * DIM * 4);        // 26.9 MB; becomes Y_l
    int*   invr  = (int*)  alloc((size_t)NN * 4);              // 512 KB
    float* x1buf = (float*)alloc((size_t)BGR * 2 * DIM * 4);   // 128 KB
    float* sc2g  = (float*)alloc((size_t)N1 * 4);              // 410 KB
    int*   indeg = (int*)  alloc((size_t)N1 * 4);              // 410 KB
    char*  h2reg = (char*) alloc((size_t)N1 * DIM * 4);        // 26.9 MB; Y_r then h2
    char*  csreg = (char*) alloc((size_t)N1 * CSRW * 4);       // 20.2 MB

    // Overlays: s1 partials in h2 region (dead before gemmB writes Y_r);
    // mean+sc1 in csr region (dead before csr_fill writes csr).
    float* Yl     = h1p;                                       // in-place
    float* Yh     = (float*)h2reg;                             // Y_r -> h2
    float* part_s = (float*)h2reg;                             // 10.5 MB
    int*   part_d = (int*)(part_s + (size_t)BGR * SPLIT * NPG1 * LB); // 2.1 MB
    int*   csr    = (int*)csreg;
    float* meanv  = (float*)csreg;                             // 2.6 MB
    float* sc1g   = meanv + (size_t)NN * LB;                   // 512 KB

    hipMemsetAsync(indeg, 0, (size_t)N1 * 4, stream);

    s1_agg_kernel<<<BGR * SPLIT, 512, 0, stream>>>(x, eidx, part_s, part_d);
    s1_score_kernel<<<NN / 256, 256, 0, stream>>>(x, part_s, part_d, c1_Wl,
                                                  c1_bl, c1_Wr, pool1_w,
                                                  meanv, sc1g);
    s1_rankpool_kernel<<<BGR, 512, 0, stream>>>(x, meanv, sc1g, c1_Wl, c1_bl,
                                                c1_Wr, h1p, invr, x1buf);
    csr_fill_kernel<<<EDG / 256, 256, 0, stream>>>(eidx, invr, csr, indeg);
    // Order matters: Yr pass reads h1p BEFORE the in-place Yl pass clobbers it.
    gemmW_kernel<true><<<GRIDW, 256, 0, stream>>>(h1p, Yh, c2_Wr, c2_bl);
    gemmW_kernel<false><<<GRIDW, 256, 0, stream>>>(h1p, Yl, c2_Wl, nullptr);
    gather2_kernel<<<GRIDA, 256, 0, stream>>>(Yl, Yh, csr, indeg, pool2_w, sc2g);
    pool2_mlp_kernel<<<BGR, 512, 0, stream>>>(sc2g, Yh, x1buf, lin1_W, lin1_b,
                                              lin2_W, lin2_b, out);
}

// Round 10
// 272.378 us; speedup vs baseline: 1.2872x; 1.2872x over previous
//
#include <hip/hip_runtime.h>
#include <hip/hip_bf16.h>

// Problem constants
#define BGR   256                 // graphs
#define NPG1  512                 // nodes per graph (input)
#define DEG   16
#define EPG   (NPG1 * DEG)        // 8192 edges per graph
#define LB    5                   // lookback features
#define DIM   64
#define OUTF  6
#define NN    (BGR * NPG1)        // 131,072
#define EDG   (BGR * EPG)         // 2,097,152
#define K1    410                 // ceil(0.8*512)
#define K2    328                 // ceil(0.8*410)
#define N1    (BGR * K1)          // 104,960
#define CSRW  48                  // CSR slots per node (max pooled in-deg ~35)
#define SPLIT 4                   // s1 aggregation sub-blocks per graph
#define EPS   (EPG / SPLIT)       // 2048 edges per sub-block
#define GRIDW (N1 / 64)           // 1640 gemm blocks (64 rows each)
#define GRIDA (N1 / 16)           // 6560 gather2 blocks

// ---------------------------------------------------------------------------
// s1_agg: per (graph, quarter) block aggregates 2048 edges into LDS, writes
// PARTIAL sums + degrees to global (no global atomics).
__global__ __launch_bounds__(512)
void s1_agg_kernel(const float* __restrict__ x,
                   const int* __restrict__ eidx,
                   float* __restrict__ part_s,
                   int* __restrict__ part_d) {
    __shared__ __align__(16) float xl[NPG1 * LB];
    __shared__ __align__(16) float sums[NPG1 * LB];
    __shared__ int degi[NPG1];

    const int bid = blockIdx.x;               // g*SPLIT + p
    const int g = bid >> 2;
    const int p = bid & 3;
    const int t = threadIdx.x;
    const int* __restrict__ src = eidx;
    const int* __restrict__ dst = eidx + EDG;

    {
        const float4* x4 = (const float4*)(x + (size_t)g * (NPG1 * LB));
        float4* xl4 = (float4*)xl;
        float4* sm4 = (float4*)sums;
        const float4 z4 = make_float4(0.f, 0.f, 0.f, 0.f);
        #pragma unroll
        for (int k = 0; k < 2; ++k) {
            int i = k * 512 + t;
            if (i < NPG1 * LB / 4) { xl4[i] = x4[i]; sm4[i] = z4; }
        }
        degi[t] = 0;
    }
    __syncthreads();

    const int ebase = g * EPG + p * EPS;
    #pragma unroll
    for (int k = 0; k < EPS / 512; ++k) {     // 4 edges per thread
        int e = ebase + k * 512 + t;
        int s = src[e] & (NPG1 - 1);
        int d = dst[e] & (NPG1 - 1);
        #pragma unroll
        for (int j = 0; j < LB; ++j)
            unsafeAtomicAdd(&sums[d * LB + j], xl[s * LB + j]);
        atomicAdd(&degi[d], 1);
    }
    __syncthreads();

    {
        float4* ps4 = (float4*)(part_s + (size_t)bid * (NPG1 * LB));
        const float4* ls4 = (const float4*)sums;
        #pragma unroll
        for (int k = 0; k < 2; ++k) {
            int i = k * 512 + t;
            if (i < NPG1 * LB / 4) ps4[i] = ls4[i];
        }
        part_d[bid * NPG1 + t] = degi[t];
    }
}

// ---------------------------------------------------------------------------
// s1_score: node-parallel, full occupancy.
__global__ __launch_bounds__(256)
void s1_score_kernel(const float* __restrict__ x,
                     const float* __restrict__ part_s,
                     const int* __restrict__ part_d,
                     const float* __restrict__ Wl,
                     const float* __restrict__ bl,
                     const float* __restrict__ Wr,
                     const float* __restrict__ pw,
                     float* __restrict__ meanv,
                     float* __restrict__ sc1g) {
    const int n = blockIdx.x * 256 + threadIdx.x;    // grid = NN/256 exact
    const int g = n >> 9, lo = n & (NPG1 - 1);

    float s0 = 0.f, s1 = 0.f, s2 = 0.f, s3 = 0.f, s4 = 0.f;
    int dg = 0;
    #pragma unroll
    for (int p = 0; p < SPLIT; ++p) {
        const float* ps = part_s + (size_t)(g * SPLIT + p) * (NPG1 * LB) + lo * LB;
        s0 += ps[0]; s1 += ps[1]; s2 += ps[2]; s3 += ps[3]; s4 += ps[4];
        dg += part_d[(g * SPLIT + p) * NPG1 + lo];
    }
    const float invd = 1.f / fmaxf((float)dg, 1.f);
    float m[LB]  = { s0 * invd, s1 * invd, s2 * invd, s3 * invd, s4 * invd };
    float xv[LB];
    const float* xr = x + (size_t)n * LB;
    #pragma unroll
    for (int j = 0; j < LB; ++j) { xv[j] = xr[j]; meanv[(size_t)n * LB + j] = m[j]; }

    const float4* Wl4 = (const float4*)Wl;
    const float4* Wr4 = (const float4*)Wr;
    const float4* bl4 = (const float4*)bl;
    const float4* pw4 = (const float4*)pw;
    float p = 0.f, q = 0.f;
    #pragma unroll 4
    for (int d4 = 0; d4 < DIM / 4; ++d4) {
        float4 bb = bl4[d4];
        float4 ww = pw4[d4];
        float4 h = bb;
        #pragma unroll
        for (int j = 0; j < LB; ++j) {
            float4 a = Wl4[j * (DIM / 4) + d4];
            float4 b = Wr4[j * (DIM / 4) + d4];
            h.x += m[j] * a.x + xv[j] * b.x;
            h.y += m[j] * a.y + xv[j] * b.y;
            h.z += m[j] * a.z + xv[j] * b.z;
            h.w += m[j] * a.w + xv[j] * b.w;
        }
        h.x = fmaxf(h.x, 0.f); h.y = fmaxf(h.y, 0.f);
        h.z = fmaxf(h.z, 0.f); h.w = fmaxf(h.w, 0.f);
        p += h.x * ww.x + h.y * ww.y + h.z * ww.z + h.w * ww.w;
        q += ww.x * ww.x + ww.y * ww.y + ww.z * ww.z + ww.w * ww.w;
    }
    sc1g[n] = tanhf(p / sqrtf(q));
}

// ---------------------------------------------------------------------------
// s1_rankpool: per-graph rank + kept-row recompute + h1p + readout x1.
__global__ __launch_bounds__(512)
void s1_rankpool_kernel(const float* __restrict__ x,
                        const float* __restrict__ meanv,
                        const float* __restrict__ sc1g,
                        const float* __restrict__ Wl,
                        const float* __restrict__ bl,
                        const float* __restrict__ Wr,
                        float* __restrict__ h1p,
                        int* __restrict__ invr,
                        float* __restrict__ x1buf) {
    __shared__ __align__(16) float sc[NPG1];
    __shared__ int   rnk[NPG1];
    __shared__ float redmx[8 * DIM];
    __shared__ float redsm[8 * DIM];

    const int g = blockIdx.x, t = threadIdx.x;
    const int wid = t >> 6, lane = t & 63;

    sc[t] = sc1g[g * NPG1 + t];
    __syncthreads();

    {
        float my = sc[t];
        int r = 0;
        const float4* sc4 = (const float4*)sc;
        #pragma unroll 4
        for (int j4 = 0; j4 < NPG1 / 4; ++j4) {
            float4 v = sc4[j4];
            int j = 4 * j4;
            r += (v.x > my) | ((v.x == my) & (j     < t));
            r += (v.y > my) | ((v.y == my) & (j + 1 < t));
            r += (v.z > my) | ((v.z == my) & (j + 2 < t));
            r += (v.w > my) | ((v.w == my) & (j + 3 < t));
        }
        rnk[t] = r;
        invr[g * NPG1 + t] = (r < K1) ? r : -1;
    }
    __syncthreads();

    float wlv[LB], wrv[LB];
    #pragma unroll
    for (int j = 0; j < LB; ++j) { wlv[j] = Wl[j * DIM + lane]; wrv[j] = Wr[j * DIM + lane]; }
    const float blv = bl[lane];

    float mx = -INFINITY, sm = 0.f;
    for (int n = wid; n < NPG1; n += 8) {
        int r = rnk[n];
        if (r >= K1) continue;
        const float* mp = meanv + (size_t)(g * NPG1 + n) * LB;
        const float* xp = x + (size_t)(g * NPG1 + n) * LB;
        float al = 0.f, ar = 0.f;
        #pragma unroll
        for (int j = 0; j < LB; ++j) {
            al += mp[j] * wlv[j];
            ar += xp[j] * wrv[j];
        }
        float acc = fmaxf(blv + al + ar, 0.f);
        float v = acc * sc[n];
        h1p[((size_t)g * K1 + r) * DIM + lane] = v;
        mx = fmaxf(mx, v);
        sm += v;
    }
    redmx[wid * DIM + lane] = mx;
    redsm[wid * DIM + lane] = sm;
    __syncthreads();
    if (wid == 0) {
        float m2 = redmx[lane], s2 = redsm[lane];
        #pragma unroll
        for (int w = 1; w < 8; ++w) {
            m2 = fmaxf(m2, redmx[w * DIM + lane]);
            s2 += redsm[w * DIM + lane];
        }
        x1buf[g * 2 * DIM + lane]       = m2;
        x1buf[g * 2 * DIM + DIM + lane] = s2 * (1.0f / (float)K1);
    }
}

// ---------------------------------------------------------------------------
// csr_fill: edge-parallel. (csr tail slots stay garbage; gather2 predicates.)
__global__ __launch_bounds__(256)
void csr_fill_kernel(const int* __restrict__ eidx,
                     const int* __restrict__ invr,
                     int* __restrict__ csr,
                     int* __restrict__ indeg) {
    int e = blockIdx.x * 256 + threadIdx.x;       // grid = EDG/256 exact
    int s = eidx[e];
    int d = eidx[EDG + e];
    int rs = invr[s];
    int rd = invr[d];
    if ((rs | rd) < 0) return;
    int g = s >> 9;
    int gn = g * K1 + rd;
    int slot = atomicAdd(&indeg[gn], 1);
    csr[gn * CSRW + slot] = g * K1 + rs;
}

// ---------------------------------------------------------------------------
// gemm2: Yl = h1p@Wl (in-place), Yr = h1p@Wr + bl — single fused pass.
// Per 64-row block: stage Wl+Wr (32KB) AND the 64 input rows (16KB) into LDS
// with coalesced loads; compute reads rows as LDS broadcasts (no VMEM
// broadcasts on the critical path). 48KB LDS -> 3 blocks/CU, 24 waves/CU.
__global__ __launch_bounds__(512)
void gemm2_kernel(float* __restrict__ hY,        // h1p in, Y_l out (in-place)
                  float* __restrict__ Yr,        // Y_r out
                  const float* __restrict__ Wl,
                  const float* __restrict__ bl,
                  const float* __restrict__ Wr) {
    __shared__ __align__(16) float wls[DIM * DIM];   // 16 KB
    __shared__ __align__(16) float wrs[DIM * DIM];   // 16 KB
    __shared__ __align__(16) float rt[64 * DIM];     // 16 KB row tile

    const int t = threadIdx.x, wid = t >> 6, lane = t & 63;
    const int cid = ((int)blockIdx.x & 7) * (GRIDW / 8) + ((int)blockIdx.x >> 3);
    const int nb = cid * 64;                     // grid = N1/64 exact

    {   // coalesced staging: weights (2x1024 float4) + rows (1024 float4)
        const float4* W4l = (const float4*)Wl;
        const float4* W4r = (const float4*)Wr;
        const float4* R4  = (const float4*)&hY[(size_t)nb * DIM];
        float4* a = (float4*)wls;
        float4* b = (float4*)wrs;
        float4* r = (float4*)rt;
        #pragma unroll
        for (int k = 0; k < 2; ++k) {
            a[k * 512 + t] = W4l[k * 512 + t];
            b[k * 512 + t] = W4r[k * 512 + t];
            r[k * 512 + t] = R4[k * 512 + t];
        }
    }
    __syncthreads();

    const int r0 = wid * 8;                      // 8 rows per wave
    float accl[8] = {0.f,0.f,0.f,0.f,0.f,0.f,0.f,0.f};
    float accr[8] = {0.f,0.f,0.f,0.f,0.f,0.f,0.f,0.f};
    #pragma unroll 4
    for (int j4 = 0; j4 < DIM / 4; ++j4) {
        const int jb = 4 * j4 * DIM + lane;
        float w0 = wls[jb],           w1 = wls[jb + DIM];
        float w2 = wls[jb + 2 * DIM], w3 = wls[jb + 3 * DIM];
        float u0 = wrs[jb],           u1 = wrs[jb + DIM];
        float u2 = wrs[jb + 2 * DIM], u3 = wrs[jb + 3 * DIM];
        #pragma unroll
        for (int i = 0; i < 8; ++i) {
            float4 a = *(const float4*)&rt[(r0 + i) * DIM + 4 * j4];
            accl[i] += a.x * w0 + a.y * w1 + a.z * w2 + a.w * w3;
            accr[i] += a.x * u0 + a.y * u1 + a.z * u2 + a.w * u3;
        }
    }
    const float bv = bl[lane];
    #pragma unroll
    for (int i = 0; i < 8; ++i) {
        hY[(size_t)(nb + r0 + i) * DIM + lane] = accl[i];
        Yr[(size_t)(nb + r0 + i) * DIM + lane] = accr[i] + bv;
    }
}

// ---------------------------------------------------------------------------
// gather2: h2 = relu(invd * sum(Y_l[nbr]) + Y_r) in-place over Yr, + score2.
__global__ __launch_bounds__(256)
void gather2_kernel(const float* __restrict__ Yl,
                    float* __restrict__ Yh,      // Y_r in, h2 out (in-place)
                    const int* __restrict__ csr,
                    const int* __restrict__ indeg,
                    const float* __restrict__ pw,
                    float* __restrict__ sc2g) {
    const int t = threadIdx.x, wid = t >> 6, lane = t & 63;
    const int cid = ((int)blockIdx.x & 7) * (GRIDA / 8) + ((int)blockIdx.x >> 3);
    const int n0 = cid * 16 + wid * 4;

    const float pwv = pw[lane];
    float q = pwv * pwv;
    #pragma unroll
    for (int o = 32; o; o >>= 1) q += __shfl_xor(q, o);
    const float inv_nrm = 1.f / sqrtf(q);

    #pragma unroll
    for (int i = 0; i < 4; ++i) {
        const int n = n0 + i;
        const int dg = indeg[n];
        const int4* cr = (const int4*)&csr[n * CSRW];
        float acc = 0.f;
        #pragma unroll 2
        for (int kc = 0; 4 * kc < dg; ++kc) {
            int4 id = cr[kc];
            int k0 = 4 * kc;
            #define GACC(idv, kk)                                          \
            {   int   _id = ((kk) < dg) ? (idv) : 0;                       \
                float _v  = Yl[(size_t)_id * DIM + lane];                  \
                acc += ((kk) < dg) ? _v : 0.f; }
            GACC(id.x, k0) GACC(id.y, k0 + 1) GACC(id.z, k0 + 2) GACC(id.w, k0 + 3)
            #undef GACC
        }
        const float invd = 1.f / fmaxf((float)dg, 1.f);
        const float h = fmaxf(acc * invd + Yh[(size_t)n * DIM + lane], 0.f);
        Yh[(size_t)n * DIM + lane] = h;
        float p = h * pwv;
        #pragma unroll
        for (int o = 32; o; o >>= 1) p += __shfl_xor(p, o);
        if (lane == 0) sc2g[n] = tanhf(p * inv_nrm);
    }
}

// ---------------------------------------------------------------------------
// Pool2 + readout2 + final MLP (one block per graph).
__global__ __launch_bounds__(512)
void pool2_mlp_kernel(const float* __restrict__ sc2g,
                      const float* __restrict__ h2,
                      const float* __restrict__ x1buf,
                      const float* __restrict__ W1,
                      const float* __restrict__ b1,
                      const float* __restrict__ W2,
                      const float* __restrict__ b2,
                      float* __restrict__ out) {
    __shared__ __align__(16) float sc2[412];
    __shared__ int   rnk2[K1];
    __shared__ float redmx[8 * DIM];
    __shared__ float redsm[8 * DIM];
    __shared__ float zy[2 * DIM + DIM];

    const int g = blockIdx.x, t = threadIdx.x;
    const int wid = t >> 6, lane = t & 63;

    if (t < K1) sc2[t] = sc2g[g * K1 + t];
    if (t >= K1 && t < 412) sc2[t] = -INFINITY;
    __syncthreads();

    if (t < K1) {
        float my = sc2[t];
        int r = 0;
        const float4* sc4 = (const float4*)sc2;
        #pragma unroll 4
        for (int j4 = 0; j4 < 103; ++j4) {
            float4 v = sc4[j4];
            int j = 4 * j4;
            r += (v.x > my) | ((v.x == my) & (j     < t));
            r += (v.y > my) | ((v.y == my) & (j + 1 < t));
            r += (v.z > my) | ((v.z == my) & (j + 2 < t));
            r += (v.w > my) | ((v.w == my) & (j + 3 < t));
        }
        rnk2[t] = r;
    }
    __syncthreads();

    float mx = -INFINITY, sm = 0.f;
    for (int n = wid; n < K1; n += 8) {
        if (rnk2[n] < K2) {
            float v = h2[((size_t)g * K1 + n) * DIM + lane] * sc2[n];
            mx = fmaxf(mx, v);
            sm += v;
        }
    }
    redmx[wid * DIM + lane] = mx;
    redsm[wid * DIM + lane] = sm;
    __syncthreads();
    if (wid == 0) {
        float m2 = redmx[lane], s2 = redsm[lane];
        #pragma unroll
        for (int w = 1; w < 8; ++w) {
            m2 = fmaxf(m2, redmx[w * DIM + lane]);
            s2 += redsm[w * DIM + lane];
        }
        zy[lane]       = x1buf[g * 2 * DIM + lane]       + m2;
        zy[DIM + lane] = x1buf[g * 2 * DIM + DIM + lane] + s2 * (1.0f / (float)K2);
    }
    __syncthreads();

    if (t < DIM) {
        float a = b1[t];
        #pragma unroll 8
        for (int j = 0; j < 2 * DIM; ++j) a += zy[j] * W1[j * DIM + t];
        zy[2 * DIM + t] = fmaxf(a, 0.f);
    }
    __syncthreads();
    if (t < OUTF) {
        float a = b2[t];
        #pragma unroll
        for (int j = 0; j < DIM; ++j) a += zy[2 * DIM + j] * W2[j * OUTF + t];
        out[g * OUTF + t] = a;
    }
}

// ---------------------------------------------------------------------------
extern "C" void kernel_launch(void* const* d_in, const int* in_sizes, int n_in,
                              void* d_out, int out_size, void* d_ws, size_t ws_size,
                              hipStream_t stream) {
    (void)in_sizes; (void)n_in; (void)out_size; (void)ws_size;
    const float* x       = (const float*)d_in[0];
    const int*   eidx    = (const int*)d_in[1];
    const float* c1_Wl   = (const float*)d_in[2];
    const float* c1_bl   = (const float*)d_in[3];
    const float* c1_Wr   = (const float*)d_in[4];
    const float* pool1_w = (const float*)d_in[5];
    const float* c2_Wl   = (const float*)d_in[6];
    const float* c2_bl   = (const float*)d_in[7];
    const float* c2_Wr   = (const float*)d_in[8];
    const float* pool2_w = (const float*)d_in[9];
    const float* lin1_W  = (const float*)d_in[10];
    const float* lin1_b  = (const float*)d_in[11];
    const float* lin2_W  = (const float*)d_in[12];
    const float* lin2_b  = (const float*)d_in[13];
    float* out = (float*)d_out;

    // Workspace layout (256-aligned), ~76 MB with overlays
    char* w = (char*)d_ws;
    size_t off = 0;
    auto alloc = [&](size_t bytes) {
        void* p = w + off;
        off = (off + bytes + 255) & ~(size_t)255;
        return p;
    };
    float* h1p   = (float*)alloc((size_t)N1 * DIM * 4);        // 26.9 MB; becomes Y_l
    int*   invr  = (int*)  alloc((size_t)NN * 4);              // 512 KB
    float* x1buf = (float*)alloc((size_t)BGR * 2 * DIM * 4);   // 128 KB
    float* sc2g  = (float*)alloc((size_t)N1 * 4);              // 410 KB
    int*   indeg = (int*)  alloc((size_t)N1 * 4);              // 410 KB
    char*  h2reg = (char*) alloc((size_t)N1 * DIM * 4);        // 26.9 MB; Y_r then h2
    char*  csreg = (char*) alloc((size_t)N1 * CSRW * 4);       // 20.2 MB

    // Overlays: s1 partials in h2 region (dead before gemm2 writes Y_r);
    // mean+sc1 in csr region (dead before csr_fill writes csr).
    float* Yl     = h1p;                                       // in-place
    float* Yh     = (float*)h2reg;                             // Y_r -> h2
    float* part_s = (float*)h2reg;                             // 10.5 MB
    int*   part_d = (int*)(part_s + (size_t)BGR * SPLIT * NPG1 * LB); // 2.1 MB
    int*   csr    = (int*)csreg;
    float* meanv  = (float*)csreg;                             // 2.6 MB
    float* sc1g   = meanv + (size_t)NN * LB;                   // 512 KB

    hipMemsetAsync(indeg, 0, (size_t)N1 * 4, stream);

    s1_agg_kernel<<<BGR * SPLIT, 512, 0, stream>>>(x, eidx, part_s, part_d);
    s1_score_kernel<<<NN / 256, 256, 0, stream>>>(x, part_s, part_d, c1_Wl,
                                                  c1_bl, c1_Wr, pool1_w,
                                                  meanv, sc1g);
    s1_rankpool_kernel<<<BGR, 512, 0, stream>>>(x, meanv, sc1g, c1_Wl, c1_bl,
                                                c1_Wr, h1p, invr, x1buf);
    csr_fill_kernel<<<EDG / 256, 256, 0, stream>>>(eidx, invr, csr, indeg);
    gemm2_kernel<<<GRIDW, 512, 0, stream>>>(h1p, Yh, c2_Wl, c2_bl, c2_Wr);
    gather2_kernel<<<GRIDA, 256, 0, stream>>>(Yl, Yh, csr, indeg, pool2_w, sc2g);
    pool2_mlp_kernel<<<BGR, 512, 0, stream>>>(sc2g, Yh, x1buf, lin1_W, lin1_b,
                                              lin2_W, lin2_b, out);
}

// Round 11
// 271.330 us; speedup vs baseline: 1.2921x; 1.0039x over previous
//
#include <hip/hip_runtime.h>
#include <hip/hip_bf16.h>

// Problem constants
#define BGR   256                 // graphs
#define NPG1  512                 // nodes per graph (input)
#define DEG   16
#define EPG   (NPG1 * DEG)        // 8192 edges per graph
#define LB    5                   // lookback features
#define DIM   64
#define OUTF  6
#define NN    (BGR * NPG1)        // 131,072
#define EDG   (BGR * EPG)         // 2,097,152
#define K1    410                 // ceil(0.8*512)
#define K2    328                 // ceil(0.8*410)
#define N1    (BGR * K1)          // 104,960
#define CSRW  48                  // layer-2 CSR slots per pooled node
#define CSRW1 56                  // layer-1 CSR slots per node (max in-deg ~40)
#define GRIDW (N1 / 64)           // 1640 gemm blocks (64 rows each)
#define GRIDA (N1 / 16)           // 6560 gather2 blocks

// ---------------------------------------------------------------------------
// csr1_fill: one int atomic per edge; dst[e] is already the global node id.
__global__ __launch_bounds__(256)
void csr1_fill_kernel(const int* __restrict__ eidx,
                      int* __restrict__ csr1,
                      int* __restrict__ indeg1) {
    int e = blockIdx.x * 256 + threadIdx.x;       // grid = EDG/256 exact
    int d = eidx[EDG + e];                        // global dst id
    int s = eidx[e] & (NPG1 - 1);                 // local src id
    int slot = atomicAdd(&indeg1[d], 1);
    if (slot < CSRW1) csr1[(size_t)d * CSRW1 + slot] = s;
}

// ---------------------------------------------------------------------------
// s1_score: node-parallel, full occupancy. Gather neighbor x-rows via CSR1
// (graph x-slice is 10 KB -> L1-resident), compute mean + conv1 + score.
__global__ __launch_bounds__(256)
void s1_score_kernel(const float* __restrict__ x,
                     const int* __restrict__ csr1,
                     const int* __restrict__ indeg1,
                     const float* __restrict__ Wl,
                     const float* __restrict__ bl,
                     const float* __restrict__ Wr,
                     const float* __restrict__ pw,
                     float* __restrict__ meanv,
                     float* __restrict__ sc1g) {
    const int n = blockIdx.x * 256 + threadIdx.x;    // grid = NN/256 exact
    const int g = n >> 9;
    const float* __restrict__ xg = x + (size_t)g * (NPG1 * LB);

    const int dgf = indeg1[n];                    // true degree (divisor)
    const int dg  = min(dgf, CSRW1);              // gather bound
    float s0 = 0.f, s1 = 0.f, s2 = 0.f, s3 = 0.f, s4 = 0.f;
    const int4* cr = (const int4*)&csr1[(size_t)n * CSRW1];
    for (int kc = 0; 4 * kc < dg; ++kc) {
        int4 id = cr[kc];
        int k0 = 4 * kc;
        #define GADD(idv, kk)                                              \
        {   int _s = ((kk) < dg) ? (idv) : 0;                              \
            const float* _xp = xg + _s * LB;                               \
            float _m = ((kk) < dg) ? 1.f : 0.f;                            \
            s0 += _m * _xp[0]; s1 += _m * _xp[1]; s2 += _m * _xp[2];       \
            s3 += _m * _xp[3]; s4 += _m * _xp[4]; }
        GADD(id.x, k0) GADD(id.y, k0 + 1) GADD(id.z, k0 + 2) GADD(id.w, k0 + 3)
        #undef GADD
    }
    const float invd = 1.f / fmaxf((float)dgf, 1.f);
    float m[LB]  = { s0 * invd, s1 * invd, s2 * invd, s3 * invd, s4 * invd };
    float xv[LB];
    const float* xr = x + (size_t)n * LB;
    #pragma unroll
    for (int j = 0; j < LB; ++j) { xv[j] = xr[j]; meanv[(size_t)n * LB + j] = m[j]; }

    const float4* Wl4 = (const float4*)Wl;
    const float4* Wr4 = (const float4*)Wr;
    const float4* bl4 = (const float4*)bl;
    const float4* pw4 = (const float4*)pw;
    float p = 0.f, q = 0.f;
    #pragma unroll 4
    for (int d4 = 0; d4 < DIM / 4; ++d4) {
        float4 bb = bl4[d4];
        float4 ww = pw4[d4];
        float4 h = bb;
        #pragma unroll
        for (int j = 0; j < LB; ++j) {
            float4 a = Wl4[j * (DIM / 4) + d4];
            float4 b = Wr4[j * (DIM / 4) + d4];
            h.x += m[j] * a.x + xv[j] * b.x;
            h.y += m[j] * a.y + xv[j] * b.y;
            h.z += m[j] * a.z + xv[j] * b.z;
            h.w += m[j] * a.w + xv[j] * b.w;
        }
        h.x = fmaxf(h.x, 0.f); h.y = fmaxf(h.y, 0.f);
        h.z = fmaxf(h.z, 0.f); h.w = fmaxf(h.w, 0.f);
        p += h.x * ww.x + h.y * ww.y + h.z * ww.z + h.w * ww.w;
        q += ww.x * ww.x + ww.y * ww.y + ww.z * ww.z + ww.w * ww.w;
    }
    sc1g[n] = tanhf(p / sqrtf(q));
}

// ---------------------------------------------------------------------------
// s1_rankpool: per-graph rank + kept-row recompute + h1p + readout x1.
__global__ __launch_bounds__(512)
void s1_rankpool_kernel(const float* __restrict__ x,
                        const float* __restrict__ meanv,
                        const float* __restrict__ sc1g,
                        const float* __restrict__ Wl,
                        const float* __restrict__ bl,
                        const float* __restrict__ Wr,
                        float* __restrict__ h1p,
                        int* __restrict__ invr,
                        float* __restrict__ x1buf) {
    __shared__ __align__(16) float sc[NPG1];
    __shared__ int   rnk[NPG1];
    __shared__ float redmx[8 * DIM];
    __shared__ float redsm[8 * DIM];

    const int g = blockIdx.x, t = threadIdx.x;
    const int wid = t >> 6, lane = t & 63;

    sc[t] = sc1g[g * NPG1 + t];
    __syncthreads();

    {
        float my = sc[t];
        int r = 0;
        const float4* sc4 = (const float4*)sc;
        #pragma unroll 4
        for (int j4 = 0; j4 < NPG1 / 4; ++j4) {
            float4 v = sc4[j4];
            int j = 4 * j4;
            r += (v.x > my) | ((v.x == my) & (j     < t));
            r += (v.y > my) | ((v.y == my) & (j + 1 < t));
            r += (v.z > my) | ((v.z == my) & (j + 2 < t));
            r += (v.w > my) | ((v.w == my) & (j + 3 < t));
        }
        rnk[t] = r;
        invr[g * NPG1 + t] = (r < K1) ? r : -1;
    }
    __syncthreads();

    float wlv[LB], wrv[LB];
    #pragma unroll
    for (int j = 0; j < LB; ++j) { wlv[j] = Wl[j * DIM + lane]; wrv[j] = Wr[j * DIM + lane]; }
    const float blv = bl[lane];

    float mx = -INFINITY, sm = 0.f;
    for (int n = wid; n < NPG1; n += 8) {
        int r = rnk[n];
        if (r >= K1) continue;
        const float* mp = meanv + (size_t)(g * NPG1 + n) * LB;
        const float* xp = x + (size_t)(g * NPG1 + n) * LB;
        float al = 0.f, ar = 0.f;
        #pragma unroll
        for (int j = 0; j < LB; ++j) {
            al += mp[j] * wlv[j];
            ar += xp[j] * wrv[j];
        }
        float acc = fmaxf(blv + al + ar, 0.f);
        float v = acc * sc[n];
        h1p[((size_t)g * K1 + r) * DIM + lane] = v;
        mx = fmaxf(mx, v);
        sm += v;
    }
    redmx[wid * DIM + lane] = mx;
    redsm[wid * DIM + lane] = sm;
    __syncthreads();
    if (wid == 0) {
        float m2 = redmx[lane], s2 = redsm[lane];
        #pragma unroll
        for (int w = 1; w < 8; ++w) {
            m2 = fmaxf(m2, redmx[w * DIM + lane]);
            s2 += redsm[w * DIM + lane];
        }
        x1buf[g * 2 * DIM + lane]       = m2;
        x1buf[g * 2 * DIM + DIM + lane] = s2 * (1.0f / (float)K1);
    }
}

// ---------------------------------------------------------------------------
// csr_fill (layer 2): edge-parallel; tail slots stay garbage (gather2 predicates).
__global__ __launch_bounds__(256)
void csr_fill_kernel(const int* __restrict__ eidx,
                     const int* __restrict__ invr,
                     int* __restrict__ csr,
                     int* __restrict__ indeg) {
    int e = blockIdx.x * 256 + threadIdx.x;       // grid = EDG/256 exact
    int s = eidx[e];
    int d = eidx[EDG + e];
    int rs = invr[s];
    int rd = invr[d];
    if ((rs | rd) < 0) return;
    int g = s >> 9;
    int gn = g * K1 + rd;
    int slot = atomicAdd(&indeg[gn], 1);
    csr[gn * CSRW + slot] = g * K1 + rs;
}

// ---------------------------------------------------------------------------
// gemm2: Yl = h1p@Wl (in-place), Yr = h1p@Wr + bl — single fused pass with
// LDS-staged weights AND row tile (no VMEM broadcasts on the critical path).
__global__ __launch_bounds__(512)
void gemm2_kernel(float* __restrict__ hY,        // h1p in, Y_l out (in-place)
                  float* __restrict__ Yr,        // Y_r out
                  const float* __restrict__ Wl,
                  const float* __restrict__ bl,
                  const float* __restrict__ Wr) {
    __shared__ __align__(16) float wls[DIM * DIM];   // 16 KB
    __shared__ __align__(16) float wrs[DIM * DIM];   // 16 KB
    __shared__ __align__(16) float rt[64 * DIM];     // 16 KB row tile

    const int t = threadIdx.x, wid = t >> 6, lane = t & 63;
    const int cid = ((int)blockIdx.x & 7) * (GRIDW / 8) + ((int)blockIdx.x >> 3);
    const int nb = cid * 64;                     // grid = N1/64 exact

    {
        const float4* W4l = (const float4*)Wl;
        const float4* W4r = (const float4*)Wr;
        const float4* R4  = (const float4*)&hY[(size_t)nb * DIM];
        float4* a = (float4*)wls;
        float4* b = (float4*)wrs;
        float4* r = (float4*)rt;
        #pragma unroll
        for (int k = 0; k < 2; ++k) {
            a[k * 512 + t] = W4l[k * 512 + t];
            b[k * 512 + t] = W4r[k * 512 + t];
            r[k * 512 + t] = R4[k * 512 + t];
        }
    }
    __syncthreads();

    const int r0 = wid * 8;                      // 8 rows per wave
    float accl[8] = {0.f,0.f,0.f,0.f,0.f,0.f,0.f,0.f};
    float accr[8] = {0.f,0.f,0.f,0.f,0.f,0.f,0.f,0.f};
    #pragma unroll 4
    for (int j4 = 0; j4 < DIM / 4; ++j4) {
        const int jb = 4 * j4 * DIM + lane;
        float w0 = wls[jb],           w1 = wls[jb + DIM];
        float w2 = wls[jb + 2 * DIM], w3 = wls[jb + 3 * DIM];
        float u0 = wrs[jb],           u1 = wrs[jb + DIM];
        float u2 = wrs[jb + 2 * DIM], u3 = wrs[jb + 3 * DIM];
        #pragma unroll
        for (int i = 0; i < 8; ++i) {
            float4 a = *(const float4*)&rt[(r0 + i) * DIM + 4 * j4];
            accl[i] += a.x * w0 + a.y * w1 + a.z * w2 + a.w * w3;
            accr[i] += a.x * u0 + a.y * u1 + a.z * u2 + a.w * u3;
        }
    }
    const float bv = bl[lane];
    #pragma unroll
    for (int i = 0; i < 8; ++i) {
        hY[(size_t)(nb + r0 + i) * DIM + lane] = accl[i];
        Yr[(size_t)(nb + r0 + i) * DIM + lane] = accr[i] + bv;
    }
}

// ---------------------------------------------------------------------------
// gather2: h2 = relu(invd * sum(Y_l[nbr]) + Y_r) in-place over Yr, + score2.
__global__ __launch_bounds__(256)
void gather2_kernel(const float* __restrict__ Yl,
                    float* __restrict__ Yh,      // Y_r in, h2 out (in-place)
                    const int* __restrict__ csr,
                    const int* __restrict__ indeg,
                    const float* __restrict__ pw,
                    float* __restrict__ sc2g) {
    const int t = threadIdx.x, wid = t >> 6, lane = t & 63;
    const int cid = ((int)blockIdx.x & 7) * (GRIDA / 8) + ((int)blockIdx.x >> 3);
    const int n0 = cid * 16 + wid * 4;

    const float pwv = pw[lane];
    float q = pwv * pwv;
    #pragma unroll
    for (int o = 32; o; o >>= 1) q += __shfl_xor(q, o);
    const float inv_nrm = 1.f / sqrtf(q);

    #pragma unroll
    for (int i = 0; i < 4; ++i) {
        const int n = n0 + i;
        const int dg = indeg[n];
        const int4* cr = (const int4*)&csr[n * CSRW];
        float acc = 0.f;
        #pragma unroll 2
        for (int kc = 0; 4 * kc < dg; ++kc) {
            int4 id = cr[kc];
            int k0 = 4 * kc;
            #define GACC(idv, kk)                                          \
            {   int   _id = ((kk) < dg) ? (idv) : 0;                       \
                float _v  = Yl[(size_t)_id * DIM + lane];                  \
                acc += ((kk) < dg) ? _v : 0.f; }
            GACC(id.x, k0) GACC(id.y, k0 + 1) GACC(id.z, k0 + 2) GACC(id.w, k0 + 3)
            #undef GACC
        }
        const float invd = 1.f / fmaxf((float)dg, 1.f);
        const float h = fmaxf(acc * invd + Yh[(size_t)n * DIM + lane], 0.f);
        Yh[(size_t)n * DIM + lane] = h;
        float p = h * pwv;
        #pragma unroll
        for (int o = 32; o; o >>= 1) p += __shfl_xor(p, o);
        if (lane == 0) sc2g[n] = tanhf(p * inv_nrm);
    }
}

// ---------------------------------------------------------------------------
// Pool2 + readout2 + final MLP (one block per graph).
__global__ __launch_bounds__(512)
void pool2_mlp_kernel(const float* __restrict__ sc2g,
                      const float* __restrict__ h2,
                      const float* __restrict__ x1buf,
                      const float* __restrict__ W1,
                      const float* __restrict__ b1,
                      const float* __restrict__ W2,
                      const float* __restrict__ b2,
                      float* __restrict__ out) {
    __shared__ __align__(16) float sc2[412];
    __shared__ int   rnk2[K1];
    __shared__ float redmx[8 * DIM];
    __shared__ float redsm[8 * DIM];
    __shared__ float zy[2 * DIM + DIM];

    const int g = blockIdx.x, t = threadIdx.x;
    const int wid = t >> 6, lane = t & 63;

    if (t < K1) sc2[t] = sc2g[g * K1 + t];
    if (t >= K1 && t < 412) sc2[t] = -INFINITY;
    __syncthreads();

    if (t < K1) {
        float my = sc2[t];
        int r = 0;
        const float4* sc4 = (const float4*)sc2;
        #pragma unroll 4
        for (int j4 = 0; j4 < 103; ++j4) {
            float4 v = sc4[j4];
            int j = 4 * j4;
            r += (v.x > my) | ((v.x == my) & (j     < t));
            r += (v.y > my) | ((v.y == my) & (j + 1 < t));
            r += (v.z > my) | ((v.z == my) & (j + 2 < t));
            r += (v.w > my) | ((v.w == my) & (j + 3 < t));
        }
        rnk2[t] = r;
    }
    __syncthreads();

    float mx = -INFINITY, sm = 0.f;
    for (int n = wid; n < K1; n += 8) {
        if (rnk2[n] < K2) {
            float v = h2[((size_t)g * K1 + n) * DIM + lane] * sc2[n];
            mx = fmaxf(mx, v);
            sm += v;
        }
    }
    redmx[wid * DIM + lane] = mx;
    redsm[wid * DIM + lane] = sm;
    __syncthreads();
    if (wid == 0) {
        float m2 = redmx[lane], s2 = redsm[lane];
        #pragma unroll
        for (int w = 1; w < 8; ++w) {
            m2 = fmaxf(m2, redmx[w * DIM + lane]);
            s2 += redsm[w * DIM + lane];
        }
        zy[lane]       = x1buf[g * 2 * DIM + lane]       + m2;
        zy[DIM + lane] = x1buf[g * 2 * DIM + DIM + lane] + s2 * (1.0f / (float)K2);
    }
    __syncthreads();

    if (t < DIM) {
        float a = b1[t];
        #pragma unroll 8
        for (int j = 0; j < 2 * DIM; ++j) a += zy[j] * W1[j * DIM + t];
        zy[2 * DIM + t] = fmaxf(a, 0.f);
    }
    __syncthreads();
    if (t < OUTF) {
        float a = b2[t];
        #pragma unroll
        for (int j = 0; j < DIM; ++j) a += zy[2 * DIM + j] * W2[j * OUTF + t];
        out[g * OUTF + t] = a;
    }
}

// ---------------------------------------------------------------------------
extern "C" void kernel_launch(void* const* d_in, const int* in_sizes, int n_in,
                              void* d_out, int out_size, void* d_ws, size_t ws_size,
                              hipStream_t stream) {
    (void)in_sizes; (void)n_in; (void)out_size; (void)ws_size;
    const float* x       = (const float*)d_in[0];
    const int*   eidx    = (const int*)d_in[1];
    const float* c1_Wl   = (const float*)d_in[2];
    const float* c1_bl   = (const float*)d_in[3];
    const float* c1_Wr   = (const float*)d_in[4];
    const float* pool1_w = (const float*)d_in[5];
    const float* c2_Wl   = (const float*)d_in[6];
    const float* c2_bl   = (const float*)d_in[7];
    const float* c2_Wr   = (const float*)d_in[8];
    const float* pool2_w = (const float*)d_in[9];
    const float* lin1_W  = (const float*)d_in[10];
    const float* lin1_b  = (const float*)d_in[11];
    const float* lin2_W  = (const float*)d_in[12];
    const float* lin2_b  = (const float*)d_in[13];
    float* out = (float*)d_out;

    // Workspace layout (256-aligned), ~78 MB with overlays
    char* w = (char*)d_ws;
    size_t off = 0;
    auto alloc = [&](size_t bytes) {
        void* p = w + off;
        off = (off + bytes + 255) & ~(size_t)255;
        return p;
    };
    float* h1p   = (float*)alloc((size_t)N1 * DIM * 4);        // 26.9 MB; becomes Y_l
    int*   invr  = (int*)  alloc((size_t)NN * 4);              // 512 KB
    float* x1buf = (float*)alloc((size_t)BGR * 2 * DIM * 4);   // 128 KB
    float* sc2g  = (float*)alloc((size_t)N1 * 4);              // 410 KB
    int*   degs  = (int*)  alloc((size_t)(N1 + NN) * 4);       // 944 KB (indeg|indeg1)
    char*  h2reg = (char*) alloc((size_t)NN * CSRW1 * 4);      // 29.4 MB; csr1 -> Yr/h2
    char*  csreg = (char*) alloc((size_t)N1 * CSRW * 4);       // 20.2 MB

    int*   indeg  = degs;                                      // N1
    int*   indeg1 = degs + N1;                                 // NN
    // Overlays: csr1 in h2reg (dead before gemm2 writes Yr);
    // mean+sc1 in csreg (dead before csr_fill writes csr2).
    float* Yl     = h1p;                                       // in-place
    float* Yh     = (float*)h2reg;                             // Y_r -> h2
    int*   csr1   = (int*)h2reg;                               // 29.4 MB
    int*   csr    = (int*)csreg;
    float* meanv  = (float*)csreg;                             // 2.6 MB
    float* sc1g   = meanv + (size_t)NN * LB;                   // 512 KB

    hipMemsetAsync(degs, 0, (size_t)(N1 + NN) * 4, stream);

    csr1_fill_kernel<<<EDG / 256, 256, 0, stream>>>(eidx, csr1, indeg1);
    s1_score_kernel<<<NN / 256, 256, 0, stream>>>(x, csr1, indeg1, c1_Wl,
                                                  c1_bl, c1_Wr, pool1_w,
                                                  meanv, sc1g);
    s1_rankpool_kernel<<<BGR, 512, 0, stream>>>(x, meanv, sc1g, c1_Wl, c1_bl,
                                                c1_Wr, h1p, invr, x1buf);
    csr_fill_kernel<<<EDG / 256, 256, 0, stream>>>(eidx, invr, csr, indeg);
    gemm2_kernel<<<GRIDW, 512, 0, stream>>>(h1p, Yh, c2_Wl, c2_bl, c2_Wr);
    gather2_kernel<<<GRIDA, 256, 0, stream>>>(Yl, Yh, csr, indeg, pool2_w, sc2g);
    pool2_mlp_kernel<<<BGR, 512, 0, stream>>>(sc2g, Yh, x1buf, lin1_W, lin1_b,
                                              lin2_W, lin2_b, out);
}

// Round 12
// 191.981 us; speedup vs baseline: 1.8262x; 1.4133x over previous
//
#include <hip/hip_runtime.h>
#include <hip/hip_bf16.h>

// Problem constants
#define BGR   256                 // graphs
#define NPG1  512                 // nodes per graph (input)
#define DEG   16
#define EPG   (NPG1 * DEG)        // 8192 edges per graph
#define LB    5                   // lookback features
#define DIM   64
#define OUTF  6
#define NN    (BGR * NPG1)        // 131,072
#define EDG   (BGR * EPG)         // 2,097,152
#define K1    410                 // ceil(0.8*512)
#define K2    328                 // ceil(0.8*410)
#define N1    (BGR * K1)          // 104,960
#define CSRW  48                  // layer-2 CSR slots per pooled node
#define CSRW1 56                  // layer-1 CSR slots per node (max in-deg ~45)
#define GRIDW (N1 / 64)           // 1640 gemm blocks (64 rows each)
#define GRIDA (N1 / 16)           // 6560 gather2 blocks

// ---------------------------------------------------------------------------
// s1_csr_score (per graph): build CSR1 entirely in LDS (u16, [slot][node]),
// then lane=node gather + conv1 + pooling score. No global CSR1, no
// scattered global writes.
__global__ __launch_bounds__(512)
void s1_csr_score_kernel(const float* __restrict__ x,
                         const int* __restrict__ eidx,
                         const float* __restrict__ Wl,
                         const float* __restrict__ bl,
                         const float* __restrict__ Wr,
                         const float* __restrict__ pw,
                         float* __restrict__ meanv,
                         float* __restrict__ sc1g) {
    __shared__ __align__(16) float xl[NPG1 * LB];              // 10 KB
    __shared__ unsigned short lcsr[CSRW1 * NPG1];              // 57.3 KB
    __shared__ int lcnt[NPG1];                                 // 2 KB

    const int g = blockIdx.x, t = threadIdx.x;
    const int* __restrict__ src = eidx;
    const int* __restrict__ dst = eidx + EDG;

    {
        const float4* x4 = (const float4*)(x + (size_t)g * (NPG1 * LB));
        float4* xl4 = (float4*)xl;
        #pragma unroll
        for (int k = 0; k < 2; ++k) {
            int i = k * 512 + t;
            if (i < NPG1 * LB / 4) xl4[i] = x4[i];
        }
        lcnt[t] = 0;
    }
    __syncthreads();

    // Edge pass: 1 LDS int atomic + 1 u16 LDS store per edge.
    const int ebase = g * EPG;
    for (int k = 0; k < EPG / 512; ++k) {
        int e = ebase + k * 512 + t;
        int s = src[e] & (NPG1 - 1);
        int d = dst[e] & (NPG1 - 1);
        int slot = atomicAdd(&lcnt[d], 1);
        if (slot < CSRW1) lcsr[slot * NPG1 + d] = (unsigned short)s;
    }
    __syncthreads();

    // Score pass: one node per thread; column reads are conflict-free.
    const int dgf = lcnt[t];
    const int dg  = min(dgf, CSRW1);
    float s0 = 0.f, s1 = 0.f, s2 = 0.f, s3 = 0.f, s4 = 0.f;
    for (int k = 0; k < dg; ++k) {
        int s = lcsr[k * NPG1 + t];
        const float* xp = xl + s * LB;
        s0 += xp[0]; s1 += xp[1]; s2 += xp[2]; s3 += xp[3]; s4 += xp[4];
    }
    const float invd = 1.f / fmaxf((float)dgf, 1.f);
    float m[LB]  = { s0 * invd, s1 * invd, s2 * invd, s3 * invd, s4 * invd };
    float xv[LB];
    const int n = g * NPG1 + t;
    #pragma unroll
    for (int j = 0; j < LB; ++j) { xv[j] = xl[t * LB + j]; meanv[(size_t)n * LB + j] = m[j]; }

    const float4* Wl4 = (const float4*)Wl;
    const float4* Wr4 = (const float4*)Wr;
    const float4* bl4 = (const float4*)bl;
    const float4* pw4 = (const float4*)pw;
    float p = 0.f, q = 0.f;
    #pragma unroll 4
    for (int d4 = 0; d4 < DIM / 4; ++d4) {
        float4 bb = bl4[d4];
        float4 ww = pw4[d4];
        float4 h = bb;
        #pragma unroll
        for (int j = 0; j < LB; ++j) {
            float4 a = Wl4[j * (DIM / 4) + d4];
            float4 b = Wr4[j * (DIM / 4) + d4];
            h.x += m[j] * a.x + xv[j] * b.x;
            h.y += m[j] * a.y + xv[j] * b.y;
            h.z += m[j] * a.z + xv[j] * b.z;
            h.w += m[j] * a.w + xv[j] * b.w;
        }
        h.x = fmaxf(h.x, 0.f); h.y = fmaxf(h.y, 0.f);
        h.z = fmaxf(h.z, 0.f); h.w = fmaxf(h.w, 0.f);
        p += h.x * ww.x + h.y * ww.y + h.z * ww.z + h.w * ww.w;
        q += ww.x * ww.x + ww.y * ww.y + ww.z * ww.z + ww.w * ww.w;
    }
    sc1g[n] = tanhf(p / sqrtf(q));
}

// ---------------------------------------------------------------------------
// s1_rankpool: per-graph rank + kept-row recompute + h1p + readout x1.
__global__ __launch_bounds__(512)
void s1_rankpool_kernel(const float* __restrict__ x,
                        const float* __restrict__ meanv,
                        const float* __restrict__ sc1g,
                        const float* __restrict__ Wl,
                        const float* __restrict__ bl,
                        const float* __restrict__ Wr,
                        float* __restrict__ h1p,
                        int* __restrict__ invr,
                        float* __restrict__ x1buf) {
    __shared__ __align__(16) float sc[NPG1];
    __shared__ int   rnk[NPG1];
    __shared__ float redmx[8 * DIM];
    __shared__ float redsm[8 * DIM];

    const int g = blockIdx.x, t = threadIdx.x;
    const int wid = t >> 6, lane = t & 63;

    sc[t] = sc1g[g * NPG1 + t];
    __syncthreads();

    {
        float my = sc[t];
        int r = 0;
        const float4* sc4 = (const float4*)sc;
        #pragma unroll 4
        for (int j4 = 0; j4 < NPG1 / 4; ++j4) {
            float4 v = sc4[j4];
            int j = 4 * j4;
            r += (v.x > my) | ((v.x == my) & (j     < t));
            r += (v.y > my) | ((v.y == my) & (j + 1 < t));
            r += (v.z > my) | ((v.z == my) & (j + 2 < t));
            r += (v.w > my) | ((v.w == my) & (j + 3 < t));
        }
        rnk[t] = r;
        invr[g * NPG1 + t] = (r < K1) ? r : -1;
    }
    __syncthreads();

    float wlv[LB], wrv[LB];
    #pragma unroll
    for (int j = 0; j < LB; ++j) { wlv[j] = Wl[j * DIM + lane]; wrv[j] = Wr[j * DIM + lane]; }
    const float blv = bl[lane];

    float mx = -INFINITY, sm = 0.f;
    for (int n = wid; n < NPG1; n += 8) {
        int r = rnk[n];
        if (r >= K1) continue;
        const float* mp = meanv + (size_t)(g * NPG1 + n) * LB;
        const float* xp = x + (size_t)(g * NPG1 + n) * LB;
        float al = 0.f, ar = 0.f;
        #pragma unroll
        for (int j = 0; j < LB; ++j) {
            al += mp[j] * wlv[j];
            ar += xp[j] * wrv[j];
        }
        float acc = fmaxf(blv + al + ar, 0.f);
        float v = acc * sc[n];
        h1p[((size_t)g * K1 + r) * DIM + lane] = v;
        mx = fmaxf(mx, v);
        sm += v;
    }
    redmx[wid * DIM + lane] = mx;
    redsm[wid * DIM + lane] = sm;
    __syncthreads();
    if (wid == 0) {
        float m2 = redmx[lane], s2 = redsm[lane];
        #pragma unroll
        for (int w = 1; w < 8; ++w) {
            m2 = fmaxf(m2, redmx[w * DIM + lane]);
            s2 += redsm[w * DIM + lane];
        }
        x1buf[g * 2 * DIM + lane]       = m2;
        x1buf[g * 2 * DIM + DIM + lane] = s2 * (1.0f / (float)K1);
    }
}

// ---------------------------------------------------------------------------
// csr2_build (per graph): filter+bucket edges into LDS u16 CSR, write out
// coalesced (10 MB total vs ~85 MB scattered) + full indeg overwrite.
__global__ __launch_bounds__(512)
void csr2_build_kernel(const int* __restrict__ eidx,
                       const int* __restrict__ invr,
                       unsigned short* __restrict__ csr2,   // [N1][CSRW] u16
                       int* __restrict__ indeg) {
    __shared__ short linv[NPG1];                             // 1 KB
    __shared__ __align__(16) unsigned short lcsr[K1 * CSRW]; // 39.4 KB
    __shared__ int lcnt[K1];                                 // 1.6 KB

    const int g = blockIdx.x, t = threadIdx.x;
    const int* __restrict__ src = eidx;
    const int* __restrict__ dst = eidx + EDG;

    if (t < NPG1) linv[t] = (short)invr[g * NPG1 + t];
    if (t < K1) lcnt[t] = 0;
    __syncthreads();

    const int ebase = g * EPG;
    for (int k = 0; k < EPG / 512; ++k) {
        int e = ebase + k * 512 + t;
        int rs = linv[src[e] & (NPG1 - 1)];
        int rd = linv[dst[e] & (NPG1 - 1)];
        if ((rs | rd) >= 0) {
            int slot = atomicAdd(&lcnt[rd], 1);
            if (slot < CSRW) lcsr[rd * CSRW + slot] = (unsigned short)rs;
        }
    }
    __syncthreads();

    {   // coalesced writeout: K1*CSRW u16 = 2460 int4
        const int4* ls4 = (const int4*)lcsr;
        int4* gs4 = (int4*)(csr2 + (size_t)g * K1 * CSRW);
        for (int i = t; i < K1 * CSRW / 8; i += 512) gs4[i] = ls4[i];
        if (t < K1) indeg[g * K1 + t] = min(lcnt[t], CSRW);
    }
}

// ---------------------------------------------------------------------------
// gemm2: Yl = h1p@Wl (in-place), Yr = h1p@Wr + bl — LDS-staged weights + rows.
__global__ __launch_bounds__(512)
void gemm2_kernel(float* __restrict__ hY,        // h1p in, Y_l out (in-place)
                  float* __restrict__ Yr,        // Y_r out
                  const float* __restrict__ Wl,
                  const float* __restrict__ bl,
                  const float* __restrict__ Wr) {
    __shared__ __align__(16) float wls[DIM * DIM];   // 16 KB
    __shared__ __align__(16) float wrs[DIM * DIM];   // 16 KB
    __shared__ __align__(16) float rt[64 * DIM];     // 16 KB row tile

    const int t = threadIdx.x, wid = t >> 6, lane = t & 63;
    const int cid = ((int)blockIdx.x & 7) * (GRIDW / 8) + ((int)blockIdx.x >> 3);
    const int nb = cid * 64;                     // grid = N1/64 exact

    {
        const float4* W4l = (const float4*)Wl;
        const float4* W4r = (const float4*)Wr;
        const float4* R4  = (const float4*)&hY[(size_t)nb * DIM];
        float4* a = (float4*)wls;
        float4* b = (float4*)wrs;
        float4* r = (float4*)rt;
        #pragma unroll
        for (int k = 0; k < 2; ++k) {
            a[k * 512 + t] = W4l[k * 512 + t];
            b[k * 512 + t] = W4r[k * 512 + t];
            r[k * 512 + t] = R4[k * 512 + t];
        }
    }
    __syncthreads();

    const int r0 = wid * 8;                      // 8 rows per wave
    float accl[8] = {0.f,0.f,0.f,0.f,0.f,0.f,0.f,0.f};
    float accr[8] = {0.f,0.f,0.f,0.f,0.f,0.f,0.f,0.f};
    #pragma unroll 4
    for (int j4 = 0; j4 < DIM / 4; ++j4) {
        const int jb = 4 * j4 * DIM + lane;
        float w0 = wls[jb],           w1 = wls[jb + DIM];
        float w2 = wls[jb + 2 * DIM], w3 = wls[jb + 3 * DIM];
        float u0 = wrs[jb],           u1 = wrs[jb + DIM];
        float u2 = wrs[jb + 2 * DIM], u3 = wrs[jb + 3 * DIM];
        #pragma unroll
        for (int i = 0; i < 8; ++i) {
            float4 a = *(const float4*)&rt[(r0 + i) * DIM + 4 * j4];
            accl[i] += a.x * w0 + a.y * w1 + a.z * w2 + a.w * w3;
            accr[i] += a.x * u0 + a.y * u1 + a.z * u2 + a.w * u3;
        }
    }
    const float bv = bl[lane];
    #pragma unroll
    for (int i = 0; i < 8; ++i) {
        hY[(size_t)(nb + r0 + i) * DIM + lane] = accl[i];
        Yr[(size_t)(nb + r0 + i) * DIM + lane] = accr[i] + bv;
    }
}

// ---------------------------------------------------------------------------
// gather2: h2 = relu(invd * sum(Y_l[nbr]) + Y_r) in-place over Yr, + score2.
// u16 CSR rows; global id = (n/K1)*K1 + local.
__global__ __launch_bounds__(256)
void gather2_kernel(const float* __restrict__ Yl,
                    float* __restrict__ Yh,      // Y_r in, h2 out (in-place)
                    const unsigned short* __restrict__ csr2,
                    const int* __restrict__ indeg,
                    const float* __restrict__ pw,
                    float* __restrict__ sc2g) {
    const int t = threadIdx.x, wid = t >> 6, lane = t & 63;
    const int cid = ((int)blockIdx.x & 7) * (GRIDA / 8) + ((int)blockIdx.x >> 3);
    const int n0 = cid * 16 + wid * 4;

    const float pwv = pw[lane];
    float q = pwv * pwv;
    #pragma unroll
    for (int o = 32; o; o >>= 1) q += __shfl_xor(q, o);
    const float inv_nrm = 1.f / sqrtf(q);

    #pragma unroll
    for (int i = 0; i < 4; ++i) {
        const int n = n0 + i;
        const int dg = indeg[n];
        const int gb = (n / K1) * K1;            // graph base (magic-mul div)
        const int4* cr = (const int4*)(csr2 + (size_t)n * CSRW); // 96B rows, 16B-aligned
        float acc = 0.f;
        for (int kc = 0; 8 * kc < dg; ++kc) {
            int4 wv = cr[kc];
            int k0 = 8 * kc;
            #define GACC(wrd, sh, kk)                                      \
            {   int _loc = ((wrd) >> (sh)) & 0xffff;                       \
                int _id  = ((kk) < dg) ? gb + _loc : 0;                    \
                float _v = Yl[(size_t)_id * DIM + lane];                   \
                acc += ((kk) < dg) ? _v : 0.f; }
            GACC(wv.x, 0, k0)     GACC(wv.x, 16, k0 + 1)
            GACC(wv.y, 0, k0 + 2) GACC(wv.y, 16, k0 + 3)
            GACC(wv.z, 0, k0 + 4) GACC(wv.z, 16, k0 + 5)
            GACC(wv.w, 0, k0 + 6) GACC(wv.w, 16, k0 + 7)
            #undef GACC
        }
        const float invd = 1.f / fmaxf((float)dg, 1.f);
        const float h = fmaxf(acc * invd + Yh[(size_t)n * DIM + lane], 0.f);
        Yh[(size_t)n * DIM + lane] = h;
        float p = h * pwv;
        #pragma unroll
        for (int o = 32; o; o >>= 1) p += __shfl_xor(p, o);
        if (lane == 0) sc2g[n] = tanhf(p * inv_nrm);
    }
}

// ---------------------------------------------------------------------------
// Pool2 + readout2 + final MLP (one block per graph).
__global__ __launch_bounds__(512)
void pool2_mlp_kernel(const float* __restrict__ sc2g,
                      const float* __restrict__ h2,
                      const float* __restrict__ x1buf,
                      const float* __restrict__ W1,
                      const float* __restrict__ b1,
                      const float* __restrict__ W2,
                      const float* __restrict__ b2,
                      float* __restrict__ out) {
    __shared__ __align__(16) float sc2[412];
    __shared__ int   rnk2[K1];
    __shared__ float redmx[8 * DIM];
    __shared__ float redsm[8 * DIM];
    __shared__ float zy[2 * DIM + DIM];

    const int g = blockIdx.x, t = threadIdx.x;
    const int wid = t >> 6, lane = t & 63;

    if (t < K1) sc2[t] = sc2g[g * K1 + t];
    if (t >= K1 && t < 412) sc2[t] = -INFINITY;
    __syncthreads();

    if (t < K1) {
        float my = sc2[t];
        int r = 0;
        const float4* sc4 = (const float4*)sc2;
        #pragma unroll 4
        for (int j4 = 0; j4 < 103; ++j4) {
            float4 v = sc4[j4];
            int j = 4 * j4;
            r += (v.x > my) | ((v.x == my) & (j     < t));
            r += (v.y > my) | ((v.y == my) & (j + 1 < t));
            r += (v.z > my) | ((v.z == my) & (j + 2 < t));
            r += (v.w > my) | ((v.w == my) & (j + 3 < t));
        }
        rnk2[t] = r;
    }
    __syncthreads();

    float mx = -INFINITY, sm = 0.f;
    for (int n = wid; n < K1; n += 8) {
        if (rnk2[n] < K2) {
            float v = h2[((size_t)g * K1 + n) * DIM + lane] * sc2[n];
            mx = fmaxf(mx, v);
            sm += v;
        }
    }
    redmx[wid * DIM + lane] = mx;
    redsm[wid * DIM + lane] = sm;
    __syncthreads();
    if (wid == 0) {
        float m2 = redmx[lane], s2 = redsm[lane];
        #pragma unroll
        for (int w = 1; w < 8; ++w) {
            m2 = fmaxf(m2, redmx[w * DIM + lane]);
            s2 += redsm[w * DIM + lane];
        }
        zy[lane]       = x1buf[g * 2 * DIM + lane]       + m2;
        zy[DIM + lane] = x1buf[g * 2 * DIM + DIM + lane] + s2 * (1.0f / (float)K2);
    }
    __syncthreads();

    if (t < DIM) {
        float a = b1[t];
        #pragma unroll 8
        for (int j = 0; j < 2 * DIM; ++j) a += zy[j] * W1[j * DIM + t];
        zy[2 * DIM + t] = fmaxf(a, 0.f);
    }
    __syncthreads();
    if (t < OUTF) {
        float a = b2[t];
        #pragma unroll
        for (int j = 0; j < DIM; ++j) a += zy[2 * DIM + j] * W2[j * OUTF + t];
        out[g * OUTF + t] = a;
    }
}

// ---------------------------------------------------------------------------
extern "C" void kernel_launch(void* const* d_in, const int* in_sizes, int n_in,
                              void* d_out, int out_size, void* d_ws, size_t ws_size,
                              hipStream_t stream) {
    (void)in_sizes; (void)n_in; (void)out_size; (void)ws_size;
    const float* x       = (const float*)d_in[0];
    const int*   eidx    = (const int*)d_in[1];
    const float* c1_Wl   = (const float*)d_in[2];
    const float* c1_bl   = (const float*)d_in[3];
    const float* c1_Wr   = (const float*)d_in[4];
    const float* pool1_w = (const float*)d_in[5];
    const float* c2_Wl   = (const float*)d_in[6];
    const float* c2_bl   = (const float*)d_in[7];
    const float* c2_Wr   = (const float*)d_in[8];
    const float* pool2_w = (const float*)d_in[9];
    const float* lin1_W  = (const float*)d_in[10];
    const float* lin1_b  = (const float*)d_in[11];
    const float* lin2_W  = (const float*)d_in[12];
    const float* lin2_b  = (const float*)d_in[13];
    float* out = (float*)d_out;

    // Workspace layout (256-aligned), ~66 MB with overlays
    char* w = (char*)d_ws;
    size_t off = 0;
    auto alloc = [&](size_t bytes) {
        void* p = w + off;
        off = (off + bytes + 255) & ~(size_t)255;
        return p;
    };
    float* h1p   = (float*)alloc((size_t)N1 * DIM * 4);        // 26.9 MB; becomes Y_l
    int*   invr  = (int*)  alloc((size_t)NN * 4);              // 512 KB
    float* x1buf = (float*)alloc((size_t)BGR * 2 * DIM * 4);   // 128 KB
    float* sc2g  = (float*)alloc((size_t)N1 * 4);              // 410 KB
    int*   indeg = (int*)  alloc((size_t)N1 * 4);              // 410 KB
    float* Yh    = (float*)alloc((size_t)N1 * DIM * 4);        // 26.9 MB; Y_r -> h2
    char*  csreg = (char*) alloc((size_t)N1 * CSRW * 2);       // 10.1 MB

    // Overlay: meanv+sc1g live in csreg, dead before csr2_build writes csr2.
    float* Yl    = h1p;                                        // in-place
    unsigned short* csr2 = (unsigned short*)csreg;
    float* meanv = (float*)csreg;                              // 2.6 MB
    float* sc1g  = meanv + (size_t)NN * LB;                    // 512 KB

    s1_csr_score_kernel<<<BGR, 512, 0, stream>>>(x, eidx, c1_Wl, c1_bl, c1_Wr,
                                                 pool1_w, meanv, sc1g);
    s1_rankpool_kernel<<<BGR, 512, 0, stream>>>(x, meanv, sc1g, c1_Wl, c1_bl,
                                                c1_Wr, h1p, invr, x1buf);
    csr2_build_kernel<<<BGR, 512, 0, stream>>>(eidx, invr, csr2, indeg);
    gemm2_kernel<<<GRIDW, 512, 0, stream>>>(h1p, Yh, c2_Wl, c2_bl, c2_Wr);
    gather2_kernel<<<GRIDA, 256, 0, stream>>>(Yl, Yh, csr2, indeg, pool2_w, sc2g);
    pool2_mlp_kernel<<<BGR, 512, 0, stream>>>(sc2g, Yh, x1buf, lin1_W, lin1_b,
                                              lin2_W, lin2_b, out);
}

// Round 13
// 183.523 us; speedup vs baseline: 1.9104x; 1.0461x over previous
//
#include <hip/hip_runtime.h>
#include <hip/hip_bf16.h>

// Problem constants
#define BGR   256                 // graphs
#define NPG1  512                 // nodes per graph (input)
#define DEG   16
#define EPG   (NPG1 * DEG)        // 8192 edges per graph
#define LB    5                   // lookback features
#define DIM   64
#define OUTF  6
#define NN    (BGR * NPG1)        // 131,072
#define EDG   (BGR * EPG)         // 2,097,152
#define K1    410                 // ceil(0.8*512)
#define K2    328                 // ceil(0.8*410)
#define N1    (BGR * K1)          // 104,960 (compact node space)
#define K1P   (K1 + 1)            // padded stride: row K1 of each graph = zeros
#define NR    (BGR * K1P)         // 105,216 padded rows (= 1644 * 64)
#define CSRW  48                  // layer-2 CSR slots per pooled node
#define CSRW1 56                  // layer-1 CSR slots per node (max in-deg ~45)
#define GRIDW (NR / 64)           // 1644 gemm blocks (64 rows each)
#define GRIDA (N1 / 16)           // 6560 gather2 blocks

// ---------------------------------------------------------------------------
// s1_csr_score (per graph): build CSR1 entirely in LDS (u16, [slot][node]),
// then lane=node gather + conv1 + pooling score.
__global__ __launch_bounds__(512)
void s1_csr_score_kernel(const float* __restrict__ x,
                         const int* __restrict__ eidx,
                         const float* __restrict__ Wl,
                         const float* __restrict__ bl,
                         const float* __restrict__ Wr,
                         const float* __restrict__ pw,
                         float* __restrict__ meanv,
                         float* __restrict__ sc1g) {
    __shared__ __align__(16) float xl[NPG1 * LB];              // 10 KB
    __shared__ unsigned short lcsr[CSRW1 * NPG1];              // 57.3 KB
    __shared__ int lcnt[NPG1];                                 // 2 KB

    const int g = blockIdx.x, t = threadIdx.x;
    const int* __restrict__ src = eidx;
    const int* __restrict__ dst = eidx + EDG;

    {
        const float4* x4 = (const float4*)(x + (size_t)g * (NPG1 * LB));
        float4* xl4 = (float4*)xl;
        #pragma unroll
        for (int k = 0; k < 2; ++k) {
            int i = k * 512 + t;
            if (i < NPG1 * LB / 4) xl4[i] = x4[i];
        }
        lcnt[t] = 0;
    }
    __syncthreads();

    const int ebase = g * EPG;
    for (int k = 0; k < EPG / 512; ++k) {
        int e = ebase + k * 512 + t;
        int s = src[e] & (NPG1 - 1);
        int d = dst[e] & (NPG1 - 1);
        int slot = atomicAdd(&lcnt[d], 1);
        if (slot < CSRW1) lcsr[slot * NPG1 + d] = (unsigned short)s;
    }
    __syncthreads();

    const int dgf = lcnt[t];
    const int dg  = min(dgf, CSRW1);
    float s0 = 0.f, s1 = 0.f, s2 = 0.f, s3 = 0.f, s4 = 0.f;
    for (int k = 0; k < dg; ++k) {
        int s = lcsr[k * NPG1 + t];
        const float* xp = xl + s * LB;
        s0 += xp[0]; s1 += xp[1]; s2 += xp[2]; s3 += xp[3]; s4 += xp[4];
    }
    const float invd = 1.f / fmaxf((float)dgf, 1.f);
    float m[LB]  = { s0 * invd, s1 * invd, s2 * invd, s3 * invd, s4 * invd };
    float xv[LB];
    const int n = g * NPG1 + t;
    #pragma unroll
    for (int j = 0; j < LB; ++j) { xv[j] = xl[t * LB + j]; meanv[(size_t)n * LB + j] = m[j]; }

    const float4* Wl4 = (const float4*)Wl;
    const float4* Wr4 = (const float4*)Wr;
    const float4* bl4 = (const float4*)bl;
    const float4* pw4 = (const float4*)pw;
    float p = 0.f, q = 0.f;
    #pragma unroll 4
    for (int d4 = 0; d4 < DIM / 4; ++d4) {
        float4 bb = bl4[d4];
        float4 ww = pw4[d4];
        float4 h = bb;
        #pragma unroll
        for (int j = 0; j < LB; ++j) {
            float4 a = Wl4[j * (DIM / 4) + d4];
            float4 b = Wr4[j * (DIM / 4) + d4];
            h.x += m[j] * a.x + xv[j] * b.x;
            h.y += m[j] * a.y + xv[j] * b.y;
            h.z += m[j] * a.z + xv[j] * b.z;
            h.w += m[j] * a.w + xv[j] * b.w;
        }
        h.x = fmaxf(h.x, 0.f); h.y = fmaxf(h.y, 0.f);
        h.z = fmaxf(h.z, 0.f); h.w = fmaxf(h.w, 0.f);
        p += h.x * ww.x + h.y * ww.y + h.z * ww.z + h.w * ww.w;
        q += ww.x * ww.x + ww.y * ww.y + ww.z * ww.z + ww.w * ww.w;
    }
    sc1g[n] = tanhf(p / sqrtf(q));
}

// ---------------------------------------------------------------------------
// s1_rankpool: per-graph rank + kept-row recompute + h1p (stride K1P, zero
// pad row) + readout x1.
__global__ __launch_bounds__(512)
void s1_rankpool_kernel(const float* __restrict__ x,
                        const float* __restrict__ meanv,
                        const float* __restrict__ sc1g,
                        const float* __restrict__ Wl,
                        const float* __restrict__ bl,
                        const float* __restrict__ Wr,
                        float* __restrict__ h1p,
                        int* __restrict__ invr,
                        float* __restrict__ x1buf) {
    __shared__ __align__(16) float sc[NPG1];
    __shared__ int   rnk[NPG1];
    __shared__ float redmx[8 * DIM];
    __shared__ float redsm[8 * DIM];

    const int g = blockIdx.x, t = threadIdx.x;
    const int wid = t >> 6, lane = t & 63;

    sc[t] = sc1g[g * NPG1 + t];
    if (t < DIM) h1p[((size_t)g * K1P + K1) * DIM + t] = 0.f;  // zero pad row
    __syncthreads();

    {
        float my = sc[t];
        int r = 0;
        const float4* sc4 = (const float4*)sc;
        #pragma unroll 4
        for (int j4 = 0; j4 < NPG1 / 4; ++j4) {
            float4 v = sc4[j4];
            int j = 4 * j4;
            r += (v.x > my) | ((v.x == my) & (j     < t));
            r += (v.y > my) | ((v.y == my) & (j + 1 < t));
            r += (v.z > my) | ((v.z == my) & (j + 2 < t));
            r += (v.w > my) | ((v.w == my) & (j + 3 < t));
        }
        rnk[t] = r;
        invr[g * NPG1 + t] = (r < K1) ? r : -1;
    }
    __syncthreads();

    float wlv[LB], wrv[LB];
    #pragma unroll
    for (int j = 0; j < LB; ++j) { wlv[j] = Wl[j * DIM + lane]; wrv[j] = Wr[j * DIM + lane]; }
    const float blv = bl[lane];

    float mx = -INFINITY, sm = 0.f;
    for (int n = wid; n < NPG1; n += 8) {
        int r = rnk[n];
        if (r >= K1) continue;
        const float* mp = meanv + (size_t)(g * NPG1 + n) * LB;
        const float* xp = x + (size_t)(g * NPG1 + n) * LB;
        float al = 0.f, ar = 0.f;
        #pragma unroll
        for (int j = 0; j < LB; ++j) {
            al += mp[j] * wlv[j];
            ar += xp[j] * wrv[j];
        }
        float acc = fmaxf(blv + al + ar, 0.f);
        float v = acc * sc[n];
        h1p[((size_t)g * K1P + r) * DIM + lane] = v;
        mx = fmaxf(mx, v);
        sm += v;
    }
    redmx[wid * DIM + lane] = mx;
    redsm[wid * DIM + lane] = sm;
    __syncthreads();
    if (wid == 0) {
        float m2 = redmx[lane], s2 = redsm[lane];
        #pragma unroll
        for (int w = 1; w < 8; ++w) {
            m2 = fmaxf(m2, redmx[w * DIM + lane]);
            s2 += redsm[w * DIM + lane];
        }
        x1buf[g * 2 * DIM + lane]       = m2;
        x1buf[g * 2 * DIM + DIM + lane] = s2 * (1.0f / (float)K1);
    }
}

// ---------------------------------------------------------------------------
// csr2_build (per graph): LDS u16 CSR pre-filled with K1 (zero-row sentinel),
// filter+bucket edges, coalesced writeout + indeg overwrite.
__global__ __launch_bounds__(512)
void csr2_build_kernel(const int* __restrict__ eidx,
                       const int* __restrict__ invr,
                       unsigned short* __restrict__ csr2,   // [N1][CSRW] u16
                       int* __restrict__ indeg) {
    __shared__ short linv[NPG1];                             // 1 KB
    __shared__ __align__(16) unsigned short lcsr[K1 * CSRW]; // 39.4 KB
    __shared__ int lcnt[K1];                                 // 1.6 KB

    const int g = blockIdx.x, t = threadIdx.x;
    const int* __restrict__ src = eidx;
    const int* __restrict__ dst = eidx + EDG;

    if (t < NPG1) linv[t] = (short)invr[g * NPG1 + t];
    if (t < K1) lcnt[t] = 0;
    {   // pre-fill all slots with sentinel K1 (per-graph zero row)
        const int fill = (K1 << 16) | K1;
        int* li = (int*)lcsr;
        for (int i = t; i < K1 * CSRW / 2; i += 512) li[i] = fill;
    }
    __syncthreads();

    const int ebase = g * EPG;
    for (int k = 0; k < EPG / 512; ++k) {
        int e = ebase + k * 512 + t;
        int rs = linv[src[e] & (NPG1 - 1)];
        int rd = linv[dst[e] & (NPG1 - 1)];
        if ((rs | rd) >= 0) {
            int slot = atomicAdd(&lcnt[rd], 1);
            if (slot < CSRW) lcsr[rd * CSRW + slot] = (unsigned short)rs;
        }
    }
    __syncthreads();

    {   // coalesced writeout: K1*CSRW u16 = 2460 int4
        const int4* ls4 = (const int4*)lcsr;
        int4* gs4 = (int4*)(csr2 + (size_t)g * K1 * CSRW);
        for (int i = t; i < K1 * CSRW / 8; i += 512) gs4[i] = ls4[i];
        if (t < K1) indeg[g * K1 + t] = min(lcnt[t], CSRW);
    }
}

// ---------------------------------------------------------------------------
// gemm2: Yl = h1p@Wl (in-place), Yr = h1p@Wr + bl over all NR padded rows.
// Zero pad rows stay zero (0@Wl = 0). LDS-staged weights + row tile.
__global__ __launch_bounds__(512)
void gemm2_kernel(float* __restrict__ hY,        // h1p in, Y_l out (in-place)
                  float* __restrict__ Yr,        // Y_r out
                  const float* __restrict__ Wl,
                  const float* __restrict__ bl,
                  const float* __restrict__ Wr) {
    __shared__ __align__(16) float wls[DIM * DIM];   // 16 KB
    __shared__ __align__(16) float wrs[DIM * DIM];   // 16 KB
    __shared__ __align__(16) float rt[64 * DIM];     // 16 KB row tile

    const int t = threadIdx.x, wid = t >> 6, lane = t & 63;
    const int nb = (int)blockIdx.x * 64;         // grid = NR/64 exact

    {
        const float4* W4l = (const float4*)Wl;
        const float4* W4r = (const float4*)Wr;
        const float4* R4  = (const float4*)&hY[(size_t)nb * DIM];
        float4* a = (float4*)wls;
        float4* b = (float4*)wrs;
        float4* r = (float4*)rt;
        #pragma unroll
        for (int k = 0; k < 2; ++k) {
            a[k * 512 + t] = W4l[k * 512 + t];
            b[k * 512 + t] = W4r[k * 512 + t];
            r[k * 512 + t] = R4[k * 512 + t];
        }
    }
    __syncthreads();

    const int r0 = wid * 8;                      // 8 rows per wave
    float accl[8] = {0.f,0.f,0.f,0.f,0.f,0.f,0.f,0.f};
    float accr[8] = {0.f,0.f,0.f,0.f,0.f,0.f,0.f,0.f};
    #pragma unroll 4
    for (int j4 = 0; j4 < DIM / 4; ++j4) {
        const int jb = 4 * j4 * DIM + lane;
        float w0 = wls[jb],           w1 = wls[jb + DIM];
        float w2 = wls[jb + 2 * DIM], w3 = wls[jb + 3 * DIM];
        float u0 = wrs[jb],           u1 = wrs[jb + DIM];
        float u2 = wrs[jb + 2 * DIM], u3 = wrs[jb + 3 * DIM];
        #pragma unroll
        for (int i = 0; i < 8; ++i) {
            float4 a = *(const float4*)&rt[(r0 + i) * DIM + 4 * j4];
            accl[i] += a.x * w0 + a.y * w1 + a.z * w2 + a.w * w3;
            accr[i] += a.x * u0 + a.y * u1 + a.z * u2 + a.w * u3;
        }
    }
    const float bv = bl[lane];
    #pragma unroll
    for (int i = 0; i < 8; ++i) {
        hY[(size_t)(nb + r0 + i) * DIM + lane] = accl[i];
        Yr[(size_t)(nb + r0 + i) * DIM + lane] = accr[i] + bv;
    }
}

// ---------------------------------------------------------------------------
// gather2: h2 = relu(invd * sum(Y_l[nbr]) + Y_r) in-place over Yr, + score2.
// Unconditional padded gather (sentinel -> per-graph zero row), scalar row
// base via readfirstlane (32-bit voffset addressing).
__global__ __launch_bounds__(256)
void gather2_kernel(const float* __restrict__ Yl,
                    float* __restrict__ Yh,      // Y_r in, h2 out (in-place)
                    const unsigned short* __restrict__ csr2,
                    const int* __restrict__ indeg,
                    const float* __restrict__ pw,
                    float* __restrict__ sc2g) {
    const int t = threadIdx.x, wid = t >> 6, lane = t & 63;
    const int cid = ((int)blockIdx.x & 7) * (GRIDA / 8) + ((int)blockIdx.x >> 3);
    const int nb = __builtin_amdgcn_readfirstlane(cid * 16 + wid * 4);

    const float pwv = pw[lane];
    float q = pwv * pwv;
    #pragma unroll
    for (int o = 32; o; o >>= 1) q += __shfl_xor(q, o);
    const float inv_nrm = 1.f / sqrtf(q);

    #pragma unroll
    for (int i = 0; i < 4; ++i) {
        const int n  = nb + i;
        const int dg = indeg[n];
        const int g  = n / K1;                   // scalar magic-mul div
        const int lr = n - g * K1;
        const float* __restrict__ bp = Yl + (size_t)g * K1P * DIM;  // scalar base
        const int4* cr = (const int4*)(csr2 + (size_t)n * CSRW);
        float a0 = 0.f, a1 = 0.f;
        const int it = (dg + 7) >> 3;
        for (int kc = 0; kc < it; ++kc) {
            int4 wv = cr[kc];                    // u16 values <= K1 (sign-safe)
            a0 += bp[((wv.x & 0xffff) << 6) + lane];
            a1 += bp[((wv.x >> 16)    << 6) + lane];
            a0 += bp[((wv.y & 0xffff) << 6) + lane];
            a1 += bp[((wv.y >> 16)    << 6) + lane];
            a0 += bp[((wv.z & 0xffff) << 6) + lane];
            a1 += bp[((wv.z >> 16)    << 6) + lane];
            a0 += bp[((wv.w & 0xffff) << 6) + lane];
            a1 += bp[((wv.w >> 16)    << 6) + lane];
        }
        const float invd = 1.f / fmaxf((float)dg, 1.f);
        float* yrow = Yh + (size_t)(g * K1P + lr) * DIM;
        const float h = fmaxf((a0 + a1) * invd + yrow[lane], 0.f);
        yrow[lane] = h;
        float p = h * pwv;
        #pragma unroll
        for (int o = 32; o; o >>= 1) p += __shfl_xor(p, o);
        if (lane == 0) sc2g[n] = tanhf(p * inv_nrm);
    }
}

// ---------------------------------------------------------------------------
// Pool2 + readout2 + final MLP (one block per graph). h2 rows at stride K1P.
__global__ __launch_bounds__(512)
void pool2_mlp_kernel(const float* __restrict__ sc2g,
                      const float* __restrict__ h2,
                      const float* __restrict__ x1buf,
                      const float* __restrict__ W1,
                      const float* __restrict__ b1,
                      const float* __restrict__ W2,
                      const float* __restrict__ b2,
                      float* __restrict__ out) {
    __shared__ __align__(16) float sc2[412];
    __shared__ int   rnk2[K1];
    __shared__ float redmx[8 * DIM];
    __shared__ float redsm[8 * DIM];
    __shared__ float zy[2 * DIM + DIM];

    const int g = blockIdx.x, t = threadIdx.x;
    const int wid = t >> 6, lane = t & 63;

    if (t < K1) sc2[t] = sc2g[g * K1 + t];
    if (t >= K1 && t < 412) sc2[t] = -INFINITY;
    __syncthreads();

    if (t < K1) {
        float my = sc2[t];
        int r = 0;
        const float4* sc4 = (const float4*)sc2;
        #pragma unroll 4
        for (int j4 = 0; j4 < 103; ++j4) {
            float4 v = sc4[j4];
            int j = 4 * j4;
            r += (v.x > my) | ((v.x == my) & (j     < t));
            r += (v.y > my) | ((v.y == my) & (j + 1 < t));
            r += (v.z > my) | ((v.z == my) & (j + 2 < t));
            r += (v.w > my) | ((v.w == my) & (j + 3 < t));
        }
        rnk2[t] = r;
    }
    __syncthreads();

    float mx = -INFINITY, sm = 0.f;
    for (int n = wid; n < K1; n += 8) {
        if (rnk2[n] < K2) {
            float v = h2[((size_t)g * K1P + n) * DIM + lane] * sc2[n];
            mx = fmaxf(mx, v);
            sm += v;
        }
    }
    redmx[wid * DIM + lane] = mx;
    redsm[wid * DIM + lane] = sm;
    __syncthreads();
    if (wid == 0) {
        float m2 = redmx[lane], s2 = redsm[lane];
        #pragma unroll
        for (int w = 1; w < 8; ++w) {
            m2 = fmaxf(m2, redmx[w * DIM + lane]);
            s2 += redsm[w * DIM + lane];
        }
        zy[lane]       = x1buf[g * 2 * DIM + lane]       + m2;
        zy[DIM + lane] = x1buf[g * 2 * DIM + DIM + lane] + s2 * (1.0f / (float)K2);
    }
    __syncthreads();

    if (t < DIM) {
        float a = b1[t];
        #pragma unroll 8
        for (int j = 0; j < 2 * DIM; ++j) a += zy[j] * W1[j * DIM + t];
        zy[2 * DIM + t] = fmaxf(a, 0.f);
    }
    __syncthreads();
    if (t < OUTF) {
        float a = b2[t];
        #pragma unroll
        for (int j = 0; j < DIM; ++j) a += zy[2 * DIM + j] * W2[j * OUTF + t];
        out[g * OUTF + t] = a;
    }
}

// ---------------------------------------------------------------------------
extern "C" void kernel_launch(void* const* d_in, const int* in_sizes, int n_in,
                              void* d_out, int out_size, void* d_ws, size_t ws_size,
                              hipStream_t stream) {
    (void)in_sizes; (void)n_in; (void)out_size; (void)ws_size;
    const float* x       = (const float*)d_in[0];
    const int*   eidx    = (const int*)d_in[1];
    const float* c1_Wl   = (const float*)d_in[2];
    const float* c1_bl   = (const float*)d_in[3];
    const float* c1_Wr   = (const float*)d_in[4];
    const float* pool1_w = (const float*)d_in[5];
    const float* c2_Wl   = (const float*)d_in[6];
    const float* c2_bl   = (const float*)d_in[7];
    const float* c2_Wr   = (const float*)d_in[8];
    const float* pool2_w = (const float*)d_in[9];
    const float* lin1_W  = (const float*)d_in[10];
    const float* lin1_b  = (const float*)d_in[11];
    const float* lin2_W  = (const float*)d_in[12];
    const float* lin2_b  = (const float*)d_in[13];
    float* out = (float*)d_out;

    // Workspace layout (256-aligned), ~66 MB with overlays
    char* w = (char*)d_ws;
    size_t off = 0;
    auto alloc = [&](size_t bytes) {
        void* p = w + off;
        off = (off + bytes + 255) & ~(size_t)255;
        return p;
    };
    float* h1p   = (float*)alloc((size_t)NR * DIM * 4);        // 26.9 MB; becomes Y_l
    int*   invr  = (int*)  alloc((size_t)NN * 4);              // 512 KB
    float* x1buf = (float*)alloc((size_t)BGR * 2 * DIM * 4);   // 128 KB
    float* sc2g  = (float*)alloc((size_t)N1 * 4);              // 410 KB
    int*   indeg = (int*)  alloc((size_t)N1 * 4);              // 410 KB
    float* Yh    = (float*)alloc((size_t)NR * DIM * 4);        // 26.9 MB; Y_r -> h2
    char*  csreg = (char*) alloc((size_t)N1 * CSRW * 2);       // 10.1 MB

    // Overlay: meanv+sc1g live in csreg, dead before csr2_build writes csr2.
    float* Yl    = h1p;                                        // in-place
    unsigned short* csr2 = (unsigned short*)csreg;
    float* meanv = (float*)csreg;                              // 2.6 MB
    float* sc1g  = meanv + (size_t)NN * LB;                    // 512 KB

    s1_csr_score_kernel<<<BGR, 512, 0, stream>>>(x, eidx, c1_Wl, c1_bl, c1_Wr,
                                                 pool1_w, meanv, sc1g);
    s1_rankpool_kernel<<<BGR, 512, 0, stream>>>(x, meanv, sc1g, c1_Wl, c1_bl,
                                                c1_Wr, h1p, invr, x1buf);
    csr2_build_kernel<<<BGR, 512, 0, stream>>>(eidx, invr, csr2, indeg);
    gemm2_kernel<<<GRIDW, 512, 0, stream>>>(h1p, Yh, c2_Wl, c2_bl, c2_Wr);
    gather2_kernel<<<GRIDA, 256, 0, stream>>>(Yl, Yh, csr2, indeg, pool2_w, sc2g);
    pool2_mlp_kernel<<<BGR, 512, 0, stream>>>(sc2g, Yh, x1buf, lin1_W, lin1_b,
                                              lin2_W, lin2_b, out);
}